// Round 1
// baseline (502.406 us; speedup 1.0000x reference)
//
#include <hip/hip_runtime.h>
#include <hip/hip_bf16.h>

__device__ __forceinline__ float lrelu_f(float v){ return v > 0.f ? v : 0.1f*v; }

// ---------------- transpose 512x512 (for kw1 -> kw1^T) ----------------
__global__ __launch_bounds__(256) void k_transpose512(const float* __restrict__ in,
                                                      float* __restrict__ out){
  __shared__ float t[32][33];
  const int bx = blockIdx.x*32, by = blockIdx.y*32;
  const int x = threadIdx.x, y = threadIdx.y;
  #pragma unroll
  for (int i=0;i<32;i+=8) t[y+i][x] = in[(by+y+i)*512 + bx + x];
  __syncthreads();
  #pragma unroll
  for (int i=0;i<32;i+=8) out[(bx+y+i)*512 + by + x] = t[x][y+i];
}

// ---------------- generic row-GEMM: Y[m][n] = act(sum_k A[m][k]*B[k][n]) ------
// MODE 0: lrelu; MODE 1: sigmoid; MODE 2: +bias[m] + E1[m][n]*E2[m][n], lrelu
template<int MODE, int MT>
__global__ __launch_bounds__(256) void k_gemm(const float* __restrict__ A,
    const float* __restrict__ B, const float* __restrict__ bias,
    const float* __restrict__ E1, const float* __restrict__ E2,
    float* __restrict__ Y, int N, int K){
  const int n  = blockIdx.y*256 + threadIdx.x;
  const int m0 = blockIdx.x*MT;
  const float* a = A + (size_t)m0*K;
  float acc[MT];
  #pragma unroll
  for (int i=0;i<MT;i++) acc[i]=0.f;
  #pragma unroll 4
  for (int k=0;k<K;k++){
    const float bv = B[(size_t)k*N + n];
    #pragma unroll
    for (int i=0;i<MT;i++) acc[i] += a[(size_t)i*K + k]*bv;
  }
  #pragma unroll
  for (int i=0;i<MT;i++){
    const int m = m0+i;
    float v = acc[i];
    if constexpr (MODE==0)      v = lrelu_f(v);
    else if constexpr (MODE==1) v = 1.f/(1.f+expf(-v));
    else { v += bias[m] + E1[(size_t)m*N+n]*E2[(size_t)m*N+n]; v = lrelu_f(v); }
    Y[(size_t)m*N+n] = v;
  }
}

// ---------------- kern[i][t] = sum_j tmp[i][j]*kw2[t][j]  (t=0..8) ------------
__global__ __launch_bounds__(64) void k_kern_gen(const float* __restrict__ tmp,
    const float* __restrict__ kw2, float* __restrict__ kern){
  const int i = blockIdx.x;
  const int lane = threadIdx.x;
  float acc[9];
  #pragma unroll
  for (int q=0;q<9;q++) acc[q]=0.f;
  for (int j=lane; j<512; j+=64){
    const float t = tmp[i*512 + j];
    #pragma unroll
    for (int q=0;q<9;q++) acc[q] += t*kw2[q*512 + j];
  }
  #pragma unroll
  for (int q=0;q<9;q++){
    float v = acc[q];
    #pragma unroll
    for (int off=32; off>0; off>>=1) v += __shfl_down(v, off);
    if (lane==0) kern[i*9+q] = v;
  }
}

// ---------------- depthwise 3x3 (SAME, zero pad), fused lrelu ----------------
__global__ __launch_bounds__(512) void k_dwconv(const float* __restrict__ x,
    const float* __restrict__ kern, float* __restrict__ y){
  const int c = blockIdx.x;
  const int p = threadIdx.x;
  const int iy = p>>5, ix = p&31;
  __shared__ float plane[18*34];
  for (int i=p;i<18*34;i+=512) plane[i]=0.f;
  __syncthreads();
  plane[(iy+1)*34 + ix+1] = x[c*512 + p];
  __syncthreads();
  const float* kp = kern + c*9;
  float s = 0.f;
  #pragma unroll
  for (int dy=0;dy<3;dy++)
    #pragma unroll
    for (int dx=0;dx<3;dx++)
      s += plane[(iy+dy)*34 + ix+dx]*kp[dy*3+dx];
  y[c*512+p] = lrelu_f(s);
}

// ---------------- dense 3x3 conv, cin-chunked partials ----------------
// grid: (64 o-tiles of 8, 4 cin chunks of 128); block: 512 threads = pixels
__global__ __launch_bounds__(512) void k_conv3x3_part(const float* __restrict__ x,
    const float* __restrict__ w, float* __restrict__ part){
  const int o0 = blockIdx.x*8;
  const int c0 = blockIdx.y*128;
  const int p = threadIdx.x;
  const int iy = p>>5, ix = p&31;
  __shared__ float plane[2][18*34];
  for (int i=p;i<18*34;i+=512){ plane[0][i]=0.f; plane[1][i]=0.f; }
  __syncthreads();
  plane[0][(iy+1)*34 + ix+1] = x[c0*512 + p];
  __syncthreads();
  float acc[8];
  #pragma unroll
  for (int i=0;i<8;i++) acc[i]=0.f;
  #pragma unroll 2
  for (int ci=0; ci<128; ci++){
    const float* pl = plane[ci&1];
    const float t00=pl[iy*34+ix],     t01=pl[iy*34+ix+1],     t02=pl[iy*34+ix+2];
    const float t10=pl[(iy+1)*34+ix], t11=pl[(iy+1)*34+ix+1], t12=pl[(iy+1)*34+ix+2];
    const float t20=pl[(iy+2)*34+ix], t21=pl[(iy+2)*34+ix+1], t22=pl[(iy+2)*34+ix+2];
    if (ci<127) plane[(ci&1)^1][(iy+1)*34 + ix+1] = x[(c0+ci+1)*512 + p];
    const float* wp = w + ((size_t)o0*512 + (c0+ci))*9;
    #pragma unroll
    for (int i=0;i<8;i++){
      const float* wi = wp + (size_t)i*4608;   // 512*9
      acc[i] += t00*wi[0]+t01*wi[1]+t02*wi[2]
              + t10*wi[3]+t11*wi[4]+t12*wi[5]
              + t20*wi[6]+t21*wi[7]+t22*wi[8];
    }
    __syncthreads();
  }
  #pragma unroll
  for (int i=0;i<8;i++)
    part[((size_t)blockIdx.y*512 + o0 + i)*512 + p] = acc[i];
}

// ---------------- reduce 4 chunks + bias (+lrelu | +residual) ----------------
template<int MODE>  // 0: lrelu ; 1: add residual, no act
__global__ __launch_bounds__(256) void k_reduce4(const float* __restrict__ part,
    const float* __restrict__ bias, const float* __restrict__ res,
    float* __restrict__ y){
  const int idx = blockIdx.x*256 + threadIdx.x;   // 0..262143
  const int o = idx>>9;
  float v = part[idx] + part[262144+idx] + part[2*262144+idx] + part[3*262144+idx]
          + bias[o];
  if constexpr (MODE==0) v = lrelu_f(v);
  else                   v += res[idx];
  y[idx] = v;
}

extern "C" void kernel_launch(void* const* d_in, const int* in_sizes, int n_in,
                              void* d_out, int out_size, void* d_ws, size_t ws_size,
                              hipStream_t stream) {
  (void)in_sizes; (void)n_in; (void)out_size; (void)ws_size;
  const float* xin    = (const float*)d_in[0];
  const float* deg    = (const float*)d_in[1];
  const float* k1_w1  = (const float*)d_in[2];
  const float* k1_w2  = (const float*)d_in[3];
  const float* p1_w   = (const float*)d_in[4];
  const float* p1_b   = (const float*)d_in[5];
  const float* ca1_w1 = (const float*)d_in[6];
  const float* ca1_w2 = (const float*)d_in[7];
  const float* conv1_w= (const float*)d_in[8];
  const float* conv1_b= (const float*)d_in[9];
  const float* k2_w1  = (const float*)d_in[10];
  const float* k2_w2  = (const float*)d_in[11];
  const float* p2_w   = (const float*)d_in[12];
  const float* p2_b   = (const float*)d_in[13];
  const float* ca2_w1 = (const float*)d_in[14];
  const float* ca2_w2 = (const float*)d_in[15];
  const float* conv2_w= (const float*)d_in[16];
  const float* conv2_b= (const float*)d_in[17];
  float* out = (float*)d_out;

  float* ws = (float*)d_ws;
  float* W1T   = ws;  ws += 262144;
  float* TMP   = ws;  ws += 262144;
  float* KERN1 = ws;  ws += 4608;
  float* KERN2 = ws;  ws += 4608;
  float* HID   = ws;  ws += 32768;
  float* ATT1  = ws;  ws += 262144;
  float* ATT2  = ws;  ws += 262144;
  float* DWL   = ws;  ws += 262144;
  float* X1    = ws;  ws += 262144;
  float* X2    = ws;  ws += 262144;
  float* PART  = ws;  ws += 4*262144;

  const dim3 tb32(32,8);

  // --- degradation-dependent precompute (kernels + attention maps) ---
  k_transpose512<<<dim3(16,16), tb32, 0, stream>>>(k1_w1, W1T);
  k_gemm<0,8><<<dim3(64,2),256,0,stream>>>(deg, W1T, nullptr,nullptr,nullptr, TMP, 512, 512);
  k_kern_gen<<<512,64,0,stream>>>(TMP, k1_w2, KERN1);
  k_transpose512<<<dim3(16,16), tb32, 0, stream>>>(k2_w1, W1T);
  k_gemm<0,8><<<dim3(64,2),256,0,stream>>>(deg, W1T, nullptr,nullptr,nullptr, TMP, 512, 512);
  k_kern_gen<<<512,64,0,stream>>>(TMP, k2_w2, KERN2);

  k_gemm<0,2><<<dim3(32,2),256,0,stream>>>(ca1_w1, deg, nullptr,nullptr,nullptr, HID, 512, 512);
  k_gemm<1,8><<<dim3(64,2),256,0,stream>>>(ca1_w2, HID, nullptr,nullptr,nullptr, ATT1, 512, 64);
  k_gemm<0,2><<<dim3(32,2),256,0,stream>>>(ca2_w1, deg, nullptr,nullptr,nullptr, HID, 512, 512);
  k_gemm<1,8><<<dim3(64,2),256,0,stream>>>(ca2_w2, HID, nullptr,nullptr,nullptr, ATT2, 512, 64);

  // --- da_conv 1 ---
  k_dwconv<<<512,512,0,stream>>>(xin, KERN1, DWL);
  k_gemm<2,8><<<dim3(64,2),256,0,stream>>>(p1_w, DWL, p1_b, deg, ATT1, X1, 512, 512);
  // --- conv1 3x3 ---
  k_conv3x3_part<<<dim3(64,4),512,0,stream>>>(X1, conv1_w, PART);
  k_reduce4<0><<<1024,256,0,stream>>>(PART, conv1_b, nullptr, X2);
  // --- da_conv 2 ---
  k_dwconv<<<512,512,0,stream>>>(X2, KERN2, DWL);
  k_gemm<2,8><<<dim3(64,2),256,0,stream>>>(p2_w, DWL, p2_b, deg, ATT2, X1, 512, 512);
  // --- conv2 3x3 + residual ---
  k_conv3x3_part<<<dim3(64,4),512,0,stream>>>(X1, conv2_w, PART);
  k_reduce4<1><<<1024,256,0,stream>>>(PART, conv2_b, xin, out);
}

// Round 3
// 381.917 us; speedup vs baseline: 1.3155x; 1.3155x over previous
//
#include <hip/hip_runtime.h>
#include <hip/hip_bf16.h>

typedef __attribute__((ext_vector_type(8))) unsigned short ushort8;
typedef __attribute__((ext_vector_type(8))) __bf16 bf16x8;
typedef __attribute__((ext_vector_type(4))) float f32x4;
typedef __attribute__((ext_vector_type(4))) unsigned short ushort4v;

__device__ __forceinline__ float lrelu_f(float v){ return v > 0.f ? v : 0.1f*v; }

__device__ __forceinline__ unsigned short f2bf(float v){
  unsigned u = __float_as_uint(v);
  unsigned r = (u + 0x7fffu + ((u>>16)&1u)) >> 16;
  return (unsigned short)r;
}

// ---------------- transpose 512x512 (for kw1 -> kw1^T) ----------------
__global__ __launch_bounds__(256) void k_transpose512(const float* __restrict__ in,
                                                      float* __restrict__ out){
  __shared__ float t[32][33];
  const int bx = blockIdx.x*32, by = blockIdx.y*32;
  const int x = threadIdx.x, y = threadIdx.y;
  #pragma unroll
  for (int i=0;i<32;i+=8) t[y+i][x] = in[(by+y+i)*512 + bx + x];
  __syncthreads();
  #pragma unroll
  for (int i=0;i<32;i+=8) out[(bx+y+i)*512 + by + x] = t[x][y+i];
}

// ---------------- generic row-GEMM: Y[m][n] = act(sum_k A[m][k]*B[k][n]) ------
// MODE 0: lrelu; MODE 1: sigmoid; MODE 2: +bias[m] + E1[m][n]*E2[m][n], lrelu
template<int MODE, int MT>
__global__ __launch_bounds__(256) void k_gemm(const float* __restrict__ A,
    const float* __restrict__ B, const float* __restrict__ bias,
    const float* __restrict__ E1, const float* __restrict__ E2,
    float* __restrict__ Y, int N, int K){
  const int n  = blockIdx.y*256 + threadIdx.x;
  const int m0 = blockIdx.x*MT;
  const float* a = A + (size_t)m0*K;
  float acc[MT];
  #pragma unroll
  for (int i=0;i<MT;i++) acc[i]=0.f;
  #pragma unroll 4
  for (int k=0;k<K;k++){
    const float bv = B[(size_t)k*N + n];
    #pragma unroll
    for (int i=0;i<MT;i++) acc[i] += a[(size_t)i*K + k]*bv;
  }
  #pragma unroll
  for (int i=0;i<MT;i++){
    const int m = m0+i;
    float v = acc[i];
    if constexpr (MODE==0)      v = lrelu_f(v);
    else if constexpr (MODE==1) v = 1.f/(1.f+expf(-v));
    else { v += bias[m] + E1[(size_t)m*N+n]*E2[(size_t)m*N+n]; v = lrelu_f(v); }
    Y[(size_t)m*N+n] = v;
  }
}

// ---------------- kern[i][t] = sum_j tmp[i][j]*kw2[t][j]  (t=0..8) ------------
__global__ __launch_bounds__(64) void k_kern_gen(const float* __restrict__ tmp,
    const float* __restrict__ kw2, float* __restrict__ kern){
  const int i = blockIdx.x;
  const int lane = threadIdx.x;
  float acc[9];
  #pragma unroll
  for (int q=0;q<9;q++) acc[q]=0.f;
  for (int j=lane; j<512; j+=64){
    const float t = tmp[i*512 + j];
    #pragma unroll
    for (int q=0;q<9;q++) acc[q] += t*kw2[q*512 + j];
  }
  #pragma unroll
  for (int q=0;q<9;q++){
    float v = acc[q];
    #pragma unroll
    for (int off=32; off>0; off>>=1) v += __shfl_down(v, off);
    if (lane==0) kern[i*9+q] = v;
  }
}

// ---------------- depthwise 3x3 (SAME, zero pad), fused lrelu ----------------
__global__ __launch_bounds__(512) void k_dwconv(const float* __restrict__ x,
    const float* __restrict__ kern, float* __restrict__ y){
  const int c = blockIdx.x;
  const int p = threadIdx.x;
  const int iy = p>>5, ix = p&31;
  __shared__ float plane[18*34];
  for (int i=p;i<18*34;i+=512) plane[i]=0.f;
  __syncthreads();
  plane[(iy+1)*34 + ix+1] = x[c*512 + p];
  __syncthreads();
  const float* kp = kern + c*9;
  float s = 0.f;
  #pragma unroll
  for (int dy=0;dy<3;dy++)
    #pragma unroll
    for (int dx=0;dx<3;dx++)
      s += plane[(iy+dy)*34 + ix+dx]*kp[dy*3+dx];
  y[c*512+p] = lrelu_f(s);
}

// ---------------- pack conv weights fp32 -> bf16 (same layout, [O][K]) -------
__global__ __launch_bounds__(256) void k_packw(const float* __restrict__ w,
    unsigned short* __restrict__ wb){
  const int i = blockIdx.x*256 + threadIdx.x;        // i over float4 groups
  const float4 v = ((const float4*)w)[i];
  ushort4v o;
  o.x = f2bf(v.x); o.y = f2bf(v.y); o.z = f2bf(v.z); o.w = f2bf(v.w);
  *(ushort4v*)(wb + (size_t)i*4) = o;
}

// ---------------- im2col: XI[p][ci*9+t] = bf16(x[ci] shifted by t) -----------
__global__ __launch_bounds__(256) void k_im2col(const float* __restrict__ x,
    unsigned short* __restrict__ XI){
  const int idx = blockIdx.x*256 + threadIdx.x;   // p*512 + ci  (ci fastest)
  const int p = idx>>9, ci = idx&511;
  const int y = p>>5, xx = p&31;
  unsigned short* dst = XI + (size_t)p*4608 + ci*9;
  const float* src = x + (size_t)ci*512;
  #pragma unroll
  for (int dy=0;dy<3;dy++){
    const int yy = y+dy-1;
    #pragma unroll
    for (int dx=0;dx<3;dx++){
      const int xc = xx+dx-1;
      float v = (yy>=0 && yy<16 && xc>=0 && xc<32) ? src[yy*32+xc] : 0.f;
      dst[dy*3+dx] = f2bf(v);
    }
  }
}

// ---------------- bf16 MFMA GEMM: C[m][n] = sum_k A[m][k]*B[n][k] ------------
// 64x64 tile, 4 waves (each 32x32), split-K=8 (KCH=576), partials to part[]
#define KCH 576
__global__ __launch_bounds__(256) void k_mfma_conv(
    const unsigned short* __restrict__ WB,
    const unsigned short* __restrict__ XI,
    float* __restrict__ part){
  __shared__ unsigned short lA[2048], lB[2048];   // 64 rows x 32 k, swizzled
  const int tid = threadIdx.x;
  const int wid = tid>>6, lane = tid&63;
  const int m0 = blockIdx.x*64, n0 = blockIdx.y*64;
  const int k0 = blockIdx.z*KCH;

  const int srow = tid>>2, skb = tid&3;           // staging: 16B per thread
  const unsigned short* gA = WB + (size_t)(m0+srow)*4608 + k0 + skb*8;
  const unsigned short* gB = XI + (size_t)(n0+srow)*4608 + k0 + skb*8;
  const int soff = srow*32 + 8*(skb ^ (srow&3));  // XOR-swizzled LDS slot

  const int wr = (wid>>1)*32, wc = (wid&1)*32;    // wave quadrant
  const int l15 = lane&15, lkb = lane>>4;
  int aoff[2], boff[2];
  #pragma unroll
  for (int s=0;s<2;s++){
    const int Ra = wr + s*16 + l15;
    aoff[s] = Ra*32 + 8*(lkb ^ (Ra&3));
    const int Rb = wc + s*16 + l15;
    boff[s] = Rb*32 + 8*(lkb ^ (Rb&3));
  }

  f32x4 acc[2][2] = {};
  for (int kk=0; kk<KCH; kk+=32){
    const ushort8 ra = *(const ushort8*)gA;
    const ushort8 rb = *(const ushort8*)gB;
    gA += 32; gB += 32;
    __syncthreads();                       // previous step's LDS reads done
    *(ushort8*)(lA + soff) = ra;
    *(ushort8*)(lB + soff) = rb;
    __syncthreads();                       // tile visible
    bf16x8 af[2], bfr[2];
    #pragma unroll
    for (int s=0;s<2;s++){
      af[s]  = *(const bf16x8*)(lA + aoff[s]);
      bfr[s] = *(const bf16x8*)(lB + boff[s]);
    }
    #pragma unroll
    for (int mi=0;mi<2;mi++)
      #pragma unroll
      for (int ni=0;ni<2;ni++)
        acc[mi][ni] = __builtin_amdgcn_mfma_f32_16x16x32_bf16(af[mi], bfr[ni], acc[mi][ni], 0,0,0);
  }

  float* pbase = part + (size_t)blockIdx.z*262144;
  #pragma unroll
  for (int mi=0;mi<2;mi++)
    #pragma unroll
    for (int ni=0;ni<2;ni++){
      const int row = m0 + wr + mi*16 + lkb*4;
      const int col = n0 + wc + ni*16 + l15;
      #pragma unroll
      for (int r=0;r<4;r++)
        pbase[(size_t)(row+r)*512 + col] = acc[mi][ni][r];
    }
}

// ---------------- reduce 8 split-K chunks + bias (+lrelu | +residual) --------
template<int MODE>  // 0: lrelu ; 1: add residual, no act
__global__ __launch_bounds__(256) void k_reduce8(const float* __restrict__ part,
    const float* __restrict__ bias, const float* __restrict__ res,
    float* __restrict__ y){
  const int idx = blockIdx.x*256 + threadIdx.x;   // 0..262143
  const int o = idx>>9;
  float v = bias[o];
  #pragma unroll
  for (int s=0;s<8;s++) v += part[(size_t)s*262144 + idx];
  if constexpr (MODE==0) v = lrelu_f(v);
  else                   v += res[idx];
  y[idx] = v;
}

extern "C" void kernel_launch(void* const* d_in, const int* in_sizes, int n_in,
                              void* d_out, int out_size, void* d_ws, size_t ws_size,
                              hipStream_t stream) {
  (void)in_sizes; (void)n_in; (void)out_size; (void)ws_size;
  const float* xin    = (const float*)d_in[0];
  const float* deg    = (const float*)d_in[1];
  const float* k1_w1  = (const float*)d_in[2];
  const float* k1_w2  = (const float*)d_in[3];
  const float* p1_w   = (const float*)d_in[4];
  const float* p1_b   = (const float*)d_in[5];
  const float* ca1_w1 = (const float*)d_in[6];
  const float* ca1_w2 = (const float*)d_in[7];
  const float* conv1_w= (const float*)d_in[8];
  const float* conv1_b= (const float*)d_in[9];
  const float* k2_w1  = (const float*)d_in[10];
  const float* k2_w2  = (const float*)d_in[11];
  const float* p2_w   = (const float*)d_in[12];
  const float* p2_b   = (const float*)d_in[13];
  const float* ca2_w1 = (const float*)d_in[14];
  const float* ca2_w2 = (const float*)d_in[15];
  const float* conv2_w= (const float*)d_in[16];
  const float* conv2_b= (const float*)d_in[17];
  float* out = (float*)d_out;

  // ---- workspace layout (byte-accurate this time) ----
  float* ws = (float*)d_ws;
  float* PART = ws;                 ws += 8*262144;   // 8 MB
  // precompute-only buffers alias the PART region (all consumed before
  // the first k_mfma_conv writes PART; stream-ordered):
  float* W1T  = PART;
  float* TMP  = PART + 262144;
  float* HID  = PART + 524288;
  float* KERN1 = ws;  ws += 4608;
  float* KERN2 = ws;  ws += 4608;
  float* ATT1  = ws;  ws += 262144;
  float* ATT2  = ws;  ws += 262144;
  float* DWL   = ws;  ws += 262144;
  float* X1    = ws;  ws += 262144;
  float* X2    = ws;  ws += 262144;
  unsigned short* WB = (unsigned short*)ws;   // 512*4608 = 2,359,296 ushorts
  unsigned short* XI = WB + 2359296;          // 2,359,296 ushorts
  // total ≈ 22.7 MB

  const dim3 tb32(32,8);

  // --- degradation-dependent precompute (kernels + attention maps) ---
  k_transpose512<<<dim3(16,16), tb32, 0, stream>>>(k1_w1, W1T);
  k_gemm<0,8><<<dim3(64,2),256,0,stream>>>(deg, W1T, nullptr,nullptr,nullptr, TMP, 512, 512);
  k_kern_gen<<<512,64,0,stream>>>(TMP, k1_w2, KERN1);
  k_transpose512<<<dim3(16,16), tb32, 0, stream>>>(k2_w1, W1T);
  k_gemm<0,8><<<dim3(64,2),256,0,stream>>>(deg, W1T, nullptr,nullptr,nullptr, TMP, 512, 512);
  k_kern_gen<<<512,64,0,stream>>>(TMP, k2_w2, KERN2);

  k_gemm<0,2><<<dim3(32,2),256,0,stream>>>(ca1_w1, deg, nullptr,nullptr,nullptr, HID, 512, 512);
  k_gemm<1,8><<<dim3(64,2),256,0,stream>>>(ca1_w2, HID, nullptr,nullptr,nullptr, ATT1, 512, 64);
  k_gemm<0,2><<<dim3(32,2),256,0,stream>>>(ca2_w1, deg, nullptr,nullptr,nullptr, HID, 512, 512);
  k_gemm<1,8><<<dim3(64,2),256,0,stream>>>(ca2_w2, HID, nullptr,nullptr,nullptr, ATT2, 512, 64);

  // --- da_conv 1 ---
  k_dwconv<<<512,512,0,stream>>>(xin, KERN1, DWL);
  k_gemm<2,8><<<dim3(64,2),256,0,stream>>>(p1_w, DWL, p1_b, deg, ATT1, X1, 512, 512);
  // --- conv1 3x3 via bf16 MFMA implicit GEMM ---
  k_packw<<<2304,256,0,stream>>>(conv1_w, WB);
  k_im2col<<<1024,256,0,stream>>>(X1, XI);
  k_mfma_conv<<<dim3(8,8,8),256,0,stream>>>(WB, XI, PART);
  k_reduce8<0><<<1024,256,0,stream>>>(PART, conv1_b, nullptr, X2);
  // --- da_conv 2 ---
  k_dwconv<<<512,512,0,stream>>>(X2, KERN2, DWL);
  k_gemm<2,8><<<dim3(64,2),256,0,stream>>>(p2_w, DWL, p2_b, deg, ATT2, X1, 512, 512);
  // --- conv2 3x3 via bf16 MFMA implicit GEMM + residual ---
  k_packw<<<2304,256,0,stream>>>(conv2_w, WB);
  k_im2col<<<1024,256,0,stream>>>(X1, XI);
  k_mfma_conv<<<dim3(8,8,8),256,0,stream>>>(WB, XI, PART);
  k_reduce8<1><<<1024,256,0,stream>>>(PART, conv2_b, xin, out);
}

// Round 4
// 157.695 us; speedup vs baseline: 3.1859x; 2.4219x over previous
//
#include <hip/hip_runtime.h>
#include <hip/hip_bf16.h>

typedef __attribute__((ext_vector_type(8))) unsigned short ushort8;
typedef __attribute__((ext_vector_type(8))) __bf16 bf16x8;
typedef __attribute__((ext_vector_type(4))) float f32x4;
typedef __attribute__((ext_vector_type(4))) unsigned short ushort4v;

__device__ __forceinline__ float lrelu_f(float v){ return v > 0.f ? v : 0.1f*v; }

__device__ __forceinline__ unsigned short f2bf(float v){
  unsigned u = __float_as_uint(v);
  unsigned r = (u + 0x7fffu + ((u>>16)&1u)) >> 16;
  return (unsigned short)r;
}

// -------- pack two f32 arrays -> bf16 (sizes in float4 quads) --------
__global__ __launch_bounds__(256) void k_pack2(
    const float* __restrict__ s0, unsigned short* __restrict__ d0, int n0q,
    const float* __restrict__ s1, unsigned short* __restrict__ d1, int n1q){
  int i = blockIdx.x*256 + threadIdx.x;
  const float* s; unsigned short* d;
  if (i < n0q){ s = s0; d = d0; }
  else { i -= n0q; if (i >= n1q) return; s = s1; d = d1; }
  const float4 v = ((const float4*)s)[i];
  ushort4v o;
  o.x=f2bf(v.x); o.y=f2bf(v.y); o.z=f2bf(v.z); o.w=f2bf(v.w);
  *(ushort4v*)(d + (size_t)i*4) = o;
}

// -------- single pack (for WB reuse, stream-ordered) --------
__global__ __launch_bounds__(256) void k_packw(const float* __restrict__ w,
    unsigned short* __restrict__ wb){
  const int i = blockIdx.x*256 + threadIdx.x;
  const float4 v = ((const float4*)w)[i];
  ushort4v o;
  o.x=f2bf(v.x); o.y=f2bf(v.y); o.z=f2bf(v.z); o.w=f2bf(v.w);
  *(ushort4v*)(wb + (size_t)i*4) = o;
}

// -------- deg: pack straight (DEGB) + transposed (DEGT), both bf16 --------
__global__ __launch_bounds__(256) void k_packtr(const float* __restrict__ in,
    unsigned short* __restrict__ db, unsigned short* __restrict__ dt){
  __shared__ float t[32][33];
  const int bx = blockIdx.x*32, by = blockIdx.y*32;
  const int x = threadIdx.x, y = threadIdx.y;
  #pragma unroll
  for (int i=0;i<32;i+=8){
    const float v = in[(size_t)(by+y+i)*512 + bx + x];
    t[y+i][x] = v;
    db[(size_t)(by+y+i)*512 + bx + x] = f2bf(v);
  }
  __syncthreads();
  #pragma unroll
  for (int i=0;i<32;i+=8)
    dt[(size_t)(bx+y+i)*512 + by + x] = f2bf(t[x][y+i]);
}

// -------- generic bf16 MFMA GEMM: C[m][n] = ep(sum_k A[m][k]*Bt[n][k]) -------
// MODE 0: lrelu -> f32 ; MODE 1: lrelu -> bf16 ; MODE 2: sigmoid -> f32 ;
// MODE 3: + bias[m] + E1[m][n]*E2[m][n], lrelu -> f32
template<int MODE>
__global__ __launch_bounds__(256) void k_mgemm(
    const unsigned short* __restrict__ A,
    const unsigned short* __restrict__ Bt,
    const float* __restrict__ bias,
    const float* __restrict__ E1, const float* __restrict__ E2,
    float* __restrict__ Cf, unsigned short* __restrict__ Cb,
    int N, int K){
  __shared__ unsigned short lA[2048], lB[2048];
  const int tid = threadIdx.x;
  const int wid = tid>>6, lane = tid&63;
  const int m0 = blockIdx.x*64, n0 = blockIdx.y*64;

  const int srow = tid>>2, skb = tid&3;
  const unsigned short* gA = A  + (size_t)(m0+srow)*K + skb*8;
  const unsigned short* gB = Bt + (size_t)(n0+srow)*K + skb*8;
  const int soff = srow*32 + 8*(skb ^ (srow&3));

  const int wr = (wid>>1)*32, wc = (wid&1)*32;
  const int l15 = lane&15, lkb = lane>>4;
  int aoff[2], boff[2];
  #pragma unroll
  for (int s=0;s<2;s++){
    const int Ra = wr + s*16 + l15;
    aoff[s] = Ra*32 + 8*(lkb ^ (Ra&3));
    const int Rb = wc + s*16 + l15;
    boff[s] = Rb*32 + 8*(lkb ^ (Rb&3));
  }

  f32x4 acc[2][2] = {};
  for (int kk=0; kk<K; kk+=32){
    const ushort8 ra = *(const ushort8*)gA;
    const ushort8 rb = *(const ushort8*)gB;
    gA += 32; gB += 32;
    __syncthreads();
    *(ushort8*)(lA + soff) = ra;
    *(ushort8*)(lB + soff) = rb;
    __syncthreads();
    bf16x8 af[2], bfr[2];
    #pragma unroll
    for (int s=0;s<2;s++){
      af[s]  = *(const bf16x8*)(lA + aoff[s]);
      bfr[s] = *(const bf16x8*)(lB + boff[s]);
    }
    #pragma unroll
    for (int mi=0;mi<2;mi++)
      #pragma unroll
      for (int ni=0;ni<2;ni++)
        acc[mi][ni] = __builtin_amdgcn_mfma_f32_16x16x32_bf16(af[mi], bfr[ni], acc[mi][ni], 0,0,0);
  }

  #pragma unroll
  for (int mi=0;mi<2;mi++)
    #pragma unroll
    for (int ni=0;ni<2;ni++){
      const int row = m0 + wr + mi*16 + lkb*4;
      const int col = n0 + wc + ni*16 + l15;
      #pragma unroll
      for (int r=0;r<4;r++){
        const int rr = row + r;
        float v = acc[mi][ni][r];
        if constexpr (MODE==0){
          Cf[(size_t)rr*N + col] = lrelu_f(v);
        } else if constexpr (MODE==1){
          Cb[(size_t)rr*N + col] = f2bf(lrelu_f(v));
        } else if constexpr (MODE==2){
          Cf[(size_t)rr*N + col] = 1.f/(1.f + expf(-v));
        } else {
          v += bias[rr] + E1[(size_t)rr*N+col]*E2[(size_t)rr*N+col];
          Cf[(size_t)rr*N + col] = lrelu_f(v);
        }
      }
    }
}

// -------- kern[i][t] = sum_j tmp[i][j]*kw2[t][j]  (t=0..8) --------
__global__ __launch_bounds__(64) void k_kern_gen(const float* __restrict__ tmp,
    const float* __restrict__ kw2, float* __restrict__ kern){
  const int i = blockIdx.x;
  const int lane = threadIdx.x;
  float acc[9];
  #pragma unroll
  for (int q=0;q<9;q++) acc[q]=0.f;
  for (int j=lane; j<512; j+=64){
    const float t = tmp[i*512 + j];
    #pragma unroll
    for (int q=0;q<9;q++) acc[q] += t*kw2[q*512 + j];
  }
  #pragma unroll
  for (int q=0;q<9;q++){
    float v = acc[q];
    #pragma unroll
    for (int off=32; off>0; off>>=1) v += __shfl_down(v, off);
    if (lane==0) kern[i*9+q] = v;
  }
}

// ---- depthwise 3x3 (SAME), fused lrelu, OUTPUT TRANSPOSED bf16 [px][ch] ----
__global__ __launch_bounds__(512) void k_dwconv(const float* __restrict__ x,
    const float* __restrict__ kern, unsigned short* __restrict__ yt){
  const int c = blockIdx.x;
  const int p = threadIdx.x;
  const int iy = p>>5, ix = p&31;
  __shared__ float plane[18*34];
  for (int i=p;i<18*34;i+=512) plane[i]=0.f;
  __syncthreads();
  plane[(iy+1)*34 + ix+1] = x[c*512 + p];
  __syncthreads();
  const float* kp = kern + c*9;
  float s = 0.f;
  #pragma unroll
  for (int dy=0;dy<3;dy++)
    #pragma unroll
    for (int dx=0;dx<3;dx++)
      s += plane[(iy+dy)*34 + ix+dx]*kp[dy*3+dx];
  yt[(size_t)p*512 + c] = f2bf(lrelu_f(s));
}

// -------- im2col: XI[p][ci*9+t] = bf16(x[ci] shifted by t) --------
__global__ __launch_bounds__(256) void k_im2col(const float* __restrict__ x,
    unsigned short* __restrict__ XI){
  const int idx = blockIdx.x*256 + threadIdx.x;
  const int p = idx>>9, ci = idx&511;
  const int y = p>>5, xx = p&31;
  unsigned short* dst = XI + (size_t)p*4608 + ci*9;
  const float* src = x + (size_t)ci*512;
  #pragma unroll
  for (int dy=0;dy<3;dy++){
    const int yy = y+dy-1;
    #pragma unroll
    for (int dx=0;dx<3;dx++){
      const int xc = xx+dx-1;
      float v = (yy>=0 && yy<16 && xc>=0 && xc<32) ? src[yy*32+xc] : 0.f;
      dst[dy*3+dx] = f2bf(v);
    }
  }
}

// -------- bf16 MFMA conv GEMM, split-K=8 (KCH=576), partials --------
#define KCH 576
__global__ __launch_bounds__(256) void k_mfma_conv(
    const unsigned short* __restrict__ WB,
    const unsigned short* __restrict__ XI,
    float* __restrict__ part){
  __shared__ unsigned short lA[2048], lB[2048];
  const int tid = threadIdx.x;
  const int wid = tid>>6, lane = tid&63;
  const int m0 = blockIdx.x*64, n0 = blockIdx.y*64;
  const int k0 = blockIdx.z*KCH;

  const int srow = tid>>2, skb = tid&3;
  const unsigned short* gA = WB + (size_t)(m0+srow)*4608 + k0 + skb*8;
  const unsigned short* gB = XI + (size_t)(n0+srow)*4608 + k0 + skb*8;
  const int soff = srow*32 + 8*(skb ^ (srow&3));

  const int wr = (wid>>1)*32, wc = (wid&1)*32;
  const int l15 = lane&15, lkb = lane>>4;
  int aoff[2], boff[2];
  #pragma unroll
  for (int s=0;s<2;s++){
    const int Ra = wr + s*16 + l15;
    aoff[s] = Ra*32 + 8*(lkb ^ (Ra&3));
    const int Rb = wc + s*16 + l15;
    boff[s] = Rb*32 + 8*(lkb ^ (Rb&3));
  }

  f32x4 acc[2][2] = {};
  for (int kk=0; kk<KCH; kk+=32){
    const ushort8 ra = *(const ushort8*)gA;
    const ushort8 rb = *(const ushort8*)gB;
    gA += 32; gB += 32;
    __syncthreads();
    *(ushort8*)(lA + soff) = ra;
    *(ushort8*)(lB + soff) = rb;
    __syncthreads();
    bf16x8 af[2], bfr[2];
    #pragma unroll
    for (int s=0;s<2;s++){
      af[s]  = *(const bf16x8*)(lA + aoff[s]);
      bfr[s] = *(const bf16x8*)(lB + boff[s]);
    }
    #pragma unroll
    for (int mi=0;mi<2;mi++)
      #pragma unroll
      for (int ni=0;ni<2;ni++)
        acc[mi][ni] = __builtin_amdgcn_mfma_f32_16x16x32_bf16(af[mi], bfr[ni], acc[mi][ni], 0,0,0);
  }

  float* pbase = part + (size_t)blockIdx.z*262144;
  #pragma unroll
  for (int mi=0;mi<2;mi++)
    #pragma unroll
    for (int ni=0;ni<2;ni++){
      const int row = m0 + wr + mi*16 + lkb*4;
      const int col = n0 + wc + ni*16 + l15;
      #pragma unroll
      for (int r=0;r<4;r++)
        pbase[(size_t)(row+r)*512 + col] = acc[mi][ni][r];
    }
}

// -------- reduce 8 split-K chunks + bias (+lrelu | +residual) --------
template<int MODE>
__global__ __launch_bounds__(256) void k_reduce8(const float* __restrict__ part,
    const float* __restrict__ bias, const float* __restrict__ res,
    float* __restrict__ y){
  const int idx = blockIdx.x*256 + threadIdx.x;
  const int o = idx>>9;
  float v = bias[o];
  #pragma unroll
  for (int s=0;s<8;s++) v += part[(size_t)s*262144 + idx];
  if constexpr (MODE==0) v = lrelu_f(v);
  else                   v += res[idx];
  y[idx] = v;
}

extern "C" void kernel_launch(void* const* d_in, const int* in_sizes, int n_in,
                              void* d_out, int out_size, void* d_ws, size_t ws_size,
                              hipStream_t stream) {
  (void)in_sizes; (void)n_in; (void)out_size; (void)ws_size;
  const float* xin    = (const float*)d_in[0];
  const float* deg    = (const float*)d_in[1];
  const float* k1_w1  = (const float*)d_in[2];
  const float* k1_w2  = (const float*)d_in[3];
  const float* p1_w   = (const float*)d_in[4];
  const float* p1_b   = (const float*)d_in[5];
  const float* ca1_w1 = (const float*)d_in[6];
  const float* ca1_w2 = (const float*)d_in[7];
  const float* conv1_w= (const float*)d_in[8];
  const float* conv1_b= (const float*)d_in[9];
  const float* k2_w1  = (const float*)d_in[10];
  const float* k2_w2  = (const float*)d_in[11];
  const float* p2_w   = (const float*)d_in[12];
  const float* p2_b   = (const float*)d_in[13];
  const float* ca2_w1 = (const float*)d_in[14];
  const float* ca2_w2 = (const float*)d_in[15];
  const float* conv2_w= (const float*)d_in[16];
  const float* conv2_b= (const float*)d_in[17];
  float* out = (float*)d_out;

  // ---- workspace (floats) ----
  float* ws = (float*)d_ws;
  float* PART = ws;  ws += 2097152;          // 8 MB, split-K partials
  // early-phase buffers alias PART (all fully consumed before the first
  // k_mfma_conv writes PART; single stream => ordered):
  float*          TMP  = PART;                               // 262144 f
  unsigned short* DEGB = (unsigned short*)(PART + 262144);   // 262144 us
  unsigned short* DEGT = DEGB + 262144;
  unsigned short* K1B  = DEGT + 262144;
  unsigned short* K2B  = K1B + 262144;
  unsigned short* P1B  = K2B + 262144;
  unsigned short* CA1A = P1B + 262144;       // 32768 us each
  unsigned short* CA1B = CA1A + 32768;
  unsigned short* CA2A = CA1B + 32768;
  unsigned short* CA2B = CA2A + 32768;
  unsigned short* HIDT1= CA2B + 32768;
  unsigned short* HIDT2= HIDT1 + 32768;      // ends < PART+8MB
  // persistent (live across conv1):
  float* KERN1 = ws;  ws += 4608;
  float* KERN2 = ws;  ws += 4608;
  float* ATT1  = ws;  ws += 262144;
  float* ATT2  = ws;  ws += 262144;
  float* X1    = ws;  ws += 262144;
  float* X2    = ws;  ws += 262144;
  unsigned short* DWLT = (unsigned short*)ws; ws += 131072;  // 262144 us
  unsigned short* P2B  = (unsigned short*)ws; ws += 131072;
  unsigned short* WB   = (unsigned short*)ws; ws += 1179648; // 2359296 us
  unsigned short* XI   = (unsigned short*)ws; ws += 1179648;

  // --- packs (independent) ---
  k_pack2<<<512,256,0,stream>>>(k1_w1, K1B, 65536, k2_w1, K2B, 65536);
  k_pack2<<<512,256,0,stream>>>(p1_w,  P1B, 65536, p2_w,  P2B, 65536);
  k_pack2<<<64, 256,0,stream>>>(ca1_w1, CA1A, 8192, ca1_w2, CA1B, 8192);
  k_pack2<<<64, 256,0,stream>>>(ca2_w1, CA2A, 8192, ca2_w2, CA2B, 8192);
  k_packtr<<<dim3(16,16),dim3(32,8),0,stream>>>(deg, DEGB, DEGT);
  k_packw<<<2304,256,0,stream>>>(conv1_w, WB);

  // --- dynamic kernels: TMP = lrelu(deg @ kw1^T); kern = TMP @ kw2^T ---
  k_mgemm<0><<<dim3(8,8),256,0,stream>>>(DEGB, K1B, nullptr,nullptr,nullptr, TMP, nullptr, 512, 512);
  k_kern_gen<<<512,64,0,stream>>>(TMP, k1_w2, KERN1);
  k_mgemm<0><<<dim3(8,8),256,0,stream>>>(DEGB, K2B, nullptr,nullptr,nullptr, TMP, nullptr, 512, 512);
  k_kern_gen<<<512,64,0,stream>>>(TMP, k2_w2, KERN2);

  // --- channel attention: HIDT = lrelu(DEGT @ ca_w1^T) ; ATT = sig(ca_w2 @ HIDT^T) ---
  k_mgemm<1><<<dim3(8,1),256,0,stream>>>(DEGT, CA1A, nullptr,nullptr,nullptr, nullptr, HIDT1, 64, 512);
  k_mgemm<2><<<dim3(8,8),256,0,stream>>>(CA1B, HIDT1, nullptr,nullptr,nullptr, ATT1, nullptr, 512, 64);
  k_mgemm<1><<<dim3(8,1),256,0,stream>>>(DEGT, CA2A, nullptr,nullptr,nullptr, nullptr, HIDT2, 64, 512);
  k_mgemm<2><<<dim3(8,8),256,0,stream>>>(CA2B, HIDT2, nullptr,nullptr,nullptr, ATT2, nullptr, 512, 64);

  // --- da_conv 1: depthwise (-> transposed bf16), pointwise MFMA GEMM ---
  k_dwconv<<<512,512,0,stream>>>(xin, KERN1, DWLT);
  k_mgemm<3><<<dim3(8,8),256,0,stream>>>(P1B, DWLT, p1_b, deg, ATT1, X1, nullptr, 512, 512);
  // --- conv1 3x3 (implicit GEMM) ---
  k_im2col<<<1024,256,0,stream>>>(X1, XI);
  k_mfma_conv<<<dim3(8,8,8),256,0,stream>>>(WB, XI, PART);
  k_reduce8<0><<<1024,256,0,stream>>>(PART, conv1_b, nullptr, X2);
  // --- da_conv 2 ---
  k_dwconv<<<512,512,0,stream>>>(X2, KERN2, DWLT);
  k_mgemm<3><<<dim3(8,8),256,0,stream>>>(P2B, DWLT, p2_b, deg, ATT2, X1, nullptr, 512, 512);
  // --- conv2 3x3 + residual ---
  k_packw<<<2304,256,0,stream>>>(conv2_w, WB);
  k_im2col<<<1024,256,0,stream>>>(X1, XI);
  k_mfma_conv<<<dim3(8,8,8),256,0,stream>>>(WB, XI, PART);
  k_reduce8<1><<<1024,256,0,stream>>>(PART, conv2_b, xin, out);
}

// Round 5
// 104.069 us; speedup vs baseline: 4.8276x; 1.5153x over previous
//
#include <hip/hip_runtime.h>
#include <hip/hip_bf16.h>

typedef __attribute__((ext_vector_type(8))) unsigned short ushort8;
typedef __attribute__((ext_vector_type(8))) __bf16 bf16x8;
typedef __attribute__((ext_vector_type(4))) float f32x4;
typedef __attribute__((ext_vector_type(4))) unsigned short ushort4v;

__device__ __forceinline__ float lrelu_f(float v){ return v > 0.f ? v : 0.1f*v; }

__device__ __forceinline__ unsigned short f2bf(float v){
  unsigned u = __float_as_uint(v);
  unsigned r = (u + 0x7fffu + ((u>>16)&1u)) >> 16;
  return (unsigned short)r;
}

__device__ __forceinline__ void packq(const float* __restrict__ s,
                                      unsigned short* __restrict__ d, int i){
  const float4 v = ((const float4*)s)[i];
  ushort4v o; o.x=f2bf(v.x); o.y=f2bf(v.y); o.z=f2bf(v.z); o.w=f2bf(v.w);
  *(ushort4v*)(d + (size_t)i*4) = o;
}

// ============ one fused pack kernel: all weights -> bf16 ============
// conv weights reordered to k = t*512 + ci (t-major) for direct-stage conv GEMM
__global__ __launch_bounds__(256) void k_pack_all(
  const float* __restrict__ k1_w1, const float* __restrict__ k2_w1,
  const float* __restrict__ p1_w,  const float* __restrict__ p2_w,
  const float* __restrict__ ca1_w1,const float* __restrict__ ca1_w2,
  const float* __restrict__ ca2_w1,const float* __restrict__ ca2_w2,
  const float* __restrict__ deg,   const float* __restrict__ conv1_w,
  const float* __restrict__ conv2_w,
  unsigned short* __restrict__ K1B, unsigned short* __restrict__ K2B,
  unsigned short* __restrict__ P1B, unsigned short* __restrict__ P2B,
  unsigned short* __restrict__ CA1A,unsigned short* __restrict__ CA1B,
  unsigned short* __restrict__ CA2A,unsigned short* __restrict__ CA2B,
  unsigned short* __restrict__ DEGB,unsigned short* __restrict__ DEGT,
  unsigned short* __restrict__ WB1, unsigned short* __restrict__ WB2){
  int i = blockIdx.x*256 + threadIdx.x;
  if (i < 65536){ packq(k1_w1, K1B, i); return; } i -= 65536;
  if (i < 65536){ packq(k2_w1, K2B, i); return; } i -= 65536;
  if (i < 65536){ packq(p1_w,  P1B, i); return; } i -= 65536;
  if (i < 65536){ packq(p2_w,  P2B, i); return; } i -= 65536;
  if (i < 8192){ packq(ca1_w1, CA1A, i); return; } i -= 8192;
  if (i < 8192){ packq(ca1_w2, CA1B, i); return; } i -= 8192;
  if (i < 8192){ packq(ca2_w1, CA2A, i); return; } i -= 8192;
  if (i < 8192){ packq(ca2_w2, CA2B, i); return; } i -= 8192;
  if (i < 65536){ packq(deg, DEGB, i); return; } i -= 65536;
  if (i < 65536){                      // DEGT: bf16 transpose of deg
    const int j = i*4; const int p = j>>9, c = j&511;
    ushort4v o;
    o.x = f2bf(deg[(size_t)(c+0)*512 + p]);
    o.y = f2bf(deg[(size_t)(c+1)*512 + p]);
    o.z = f2bf(deg[(size_t)(c+2)*512 + p]);
    o.w = f2bf(deg[(size_t)(c+3)*512 + p]);
    *(ushort4v*)(DEGT + (size_t)j) = o;
    return;
  } i -= 65536;
  if (i < 589824){                     // WB1: [o][t*512+ci] = w[o][ci*9+t]
    const int o_ = i/1152; const int r4 = (i - o_*1152)*4;
    const int t = r4>>9; const int ci = r4&511;
    const float* s = conv1_w + (size_t)o_*4608;
    ushort4v o;
    o.x = f2bf(s[(ci+0)*9 + t]); o.y = f2bf(s[(ci+1)*9 + t]);
    o.z = f2bf(s[(ci+2)*9 + t]); o.w = f2bf(s[(ci+3)*9 + t]);
    *(ushort4v*)(WB1 + (size_t)o_*4608 + r4) = o;
    return;
  } i -= 589824;
  if (i < 589824){                     // WB2
    const int o_ = i/1152; const int r4 = (i - o_*1152)*4;
    const int t = r4>>9; const int ci = r4&511;
    const float* s = conv2_w + (size_t)o_*4608;
    ushort4v o;
    o.x = f2bf(s[(ci+0)*9 + t]); o.y = f2bf(s[(ci+1)*9 + t]);
    o.z = f2bf(s[(ci+2)*9 + t]); o.w = f2bf(s[(ci+3)*9 + t]);
    *(ushort4v*)(WB2 + (size_t)o_*4608 + r4) = o;
  }
}

// ======= bf16 MFMA GEMM, z-batched: C[m][n] = ep(sum_k A[m][k]*Bt[n][k]) =====
// MODE 0: lrelu -> f32 ; MODE 1: lrelu -> bf16 [m][n] ; MODE 2: sigmoid -> f32
// MODE 4: +bias[m]+E1[m][n]*E2[m][n], lrelu -> bf16 TRANSPOSED [n][m] (XT)
template<int MODE>
__global__ __launch_bounds__(256) void k_mgemm(
    const unsigned short* __restrict__ A0, const unsigned short* __restrict__ A1,
    const unsigned short* __restrict__ B0, const unsigned short* __restrict__ B1,
    const float* __restrict__ bias,
    const float* __restrict__ E1, const float* __restrict__ E2,
    float* __restrict__ Cf0, float* __restrict__ Cf1,
    unsigned short* __restrict__ Cb0, unsigned short* __restrict__ Cb1,
    int N, int K){
  const unsigned short* A  = blockIdx.z ? A1 : A0;
  const unsigned short* Bt = blockIdx.z ? B1 : B0;
  float* Cf          = blockIdx.z ? Cf1 : Cf0;
  unsigned short* Cb = blockIdx.z ? Cb1 : Cb0;

  __shared__ unsigned short lA[2048], lB[2048];
  const int tid = threadIdx.x;
  const int wid = tid>>6, lane = tid&63;
  const int m0 = blockIdx.x*64, n0 = blockIdx.y*64;

  const int srow = tid>>2, skb = tid&3;
  const unsigned short* gA = A  + (size_t)(m0+srow)*K + skb*8;
  const unsigned short* gB = Bt + (size_t)(n0+srow)*K + skb*8;
  const int soff = srow*32 + 8*(skb ^ (srow&3));

  const int wr = (wid>>1)*32, wc = (wid&1)*32;
  const int l15 = lane&15, lkb = lane>>4;
  int aoff[2], boff[2];
  #pragma unroll
  for (int s=0;s<2;s++){
    const int Ra = wr + s*16 + l15;
    aoff[s] = Ra*32 + 8*(lkb ^ (Ra&3));
    const int Rb = wc + s*16 + l15;
    boff[s] = Rb*32 + 8*(lkb ^ (Rb&3));
  }

  f32x4 acc[2][2] = {};
  for (int kk=0; kk<K; kk+=32){
    const ushort8 ra = *(const ushort8*)gA;
    const ushort8 rb = *(const ushort8*)gB;
    gA += 32; gB += 32;
    __syncthreads();
    *(ushort8*)(lA + soff) = ra;
    *(ushort8*)(lB + soff) = rb;
    __syncthreads();
    bf16x8 af[2], bfr[2];
    #pragma unroll
    for (int s=0;s<2;s++){
      af[s]  = *(const bf16x8*)(lA + aoff[s]);
      bfr[s] = *(const bf16x8*)(lB + boff[s]);
    }
    #pragma unroll
    for (int mi=0;mi<2;mi++)
      #pragma unroll
      for (int ni=0;ni<2;ni++)
        acc[mi][ni] = __builtin_amdgcn_mfma_f32_16x16x32_bf16(af[mi], bfr[ni], acc[mi][ni], 0,0,0);
  }

  if constexpr (MODE==4){
    __shared__ float tile[64][65];
    #pragma unroll
    for (int mi=0;mi<2;mi++)
      #pragma unroll
      for (int ni=0;ni<2;ni++){
        const int rl = wr + mi*16 + lkb*4;
        const int cl = wc + ni*16 + l15;
        #pragma unroll
        for (int r=0;r<4;r++){
          const int rr = m0 + rl + r, col = n0 + cl;
          float v = acc[mi][ni][r] + bias[rr] + E1[(size_t)rr*512+col]*E2[(size_t)rr*512+col];
          tile[rl+r][cl] = lrelu_f(v);
        }
      }
    __syncthreads();
    const int r = tid>>2, q = tid&3;         // pixel row r, channel quad q
    ushort8 o0, o1;
    #pragma unroll
    for (int j=0;j<8;j++)  o0[j] = f2bf(tile[q*16+j][r]);
    #pragma unroll
    for (int j=0;j<8;j++)  o1[j] = f2bf(tile[q*16+8+j][r]);
    unsigned short* dst = Cb + (size_t)(n0+r)*512 + m0 + q*16;
    *(ushort8*)dst = o0;
    *(ushort8*)(dst+8) = o1;
  } else {
    #pragma unroll
    for (int mi=0;mi<2;mi++)
      #pragma unroll
      for (int ni=0;ni<2;ni++){
        const int row = m0 + wr + mi*16 + lkb*4;
        const int col = n0 + wc + ni*16 + l15;
        #pragma unroll
        for (int r=0;r<4;r++){
          const int rr = row + r;
          float v = acc[mi][ni][r];
          if constexpr (MODE==0)      Cf[(size_t)rr*N + col] = lrelu_f(v);
          else if constexpr (MODE==1) Cb[(size_t)rr*N + col] = f2bf(lrelu_f(v));
          else                        Cf[(size_t)rr*N + col] = 1.f/(1.f + expf(-v));
        }
      }
  }
}

// ===== kern[i][t] = sum_j tmp[i][j]*kw2[t][j], z-batched over the 2 branches ==
__global__ __launch_bounds__(64) void k_kern_gen(
    const float* __restrict__ tmp0, const float* __restrict__ tmp1,
    const float* __restrict__ kw2a, const float* __restrict__ kw2b,
    float* __restrict__ kern0, float* __restrict__ kern1){
  const float* tmp  = blockIdx.y ? tmp1  : tmp0;
  const float* kw2  = blockIdx.y ? kw2b  : kw2a;
  float* kern       = blockIdx.y ? kern1 : kern0;
  const int i = blockIdx.x;
  const int lane = threadIdx.x;
  float acc[9];
  #pragma unroll
  for (int q=0;q<9;q++) acc[q]=0.f;
  for (int j=lane; j<512; j+=64){
    const float t = tmp[i*512 + j];
    #pragma unroll
    for (int q=0;q<9;q++) acc[q] += t*kw2[q*512 + j];
  }
  #pragma unroll
  for (int q=0;q<9;q++){
    float v = acc[q];
    #pragma unroll
    for (int off=32; off>0; off>>=1) v += __shfl_down(v, off);
    if (lane==0) kern[i*9+q] = v;
  }
}

// ==== depthwise 3x3 (SAME) + lrelu, f32 input, OUT transposed bf16 [px][ch] ===
__global__ __launch_bounds__(512) void k_dwconv(const float* __restrict__ x,
    const float* __restrict__ kern, unsigned short* __restrict__ yt){
  const int c = blockIdx.x;
  const int p = threadIdx.x;
  const int iy = p>>5, ix = p&31;
  __shared__ float plane[18*34];
  for (int i=p;i<18*34;i+=512) plane[i]=0.f;
  __syncthreads();
  plane[(iy+1)*34 + ix+1] = x[c*512 + p];
  __syncthreads();
  const float* kp = kern + c*9;
  float s = 0.f;
  #pragma unroll
  for (int dy=0;dy<3;dy++)
    #pragma unroll
    for (int dx=0;dx<3;dx++)
      s += plane[(iy+dy)*34 + ix+dx]*kp[dy*3+dx];
  yt[(size_t)p*512 + c] = f2bf(lrelu_f(s));
}

// ==== fused: X2 row = lrelu(bias + sum8 partials), then depthwise -> DWLT ====
__global__ __launch_bounds__(512) void k_dwconv_red(const float* __restrict__ part,
    const float* __restrict__ bias, const float* __restrict__ kern,
    unsigned short* __restrict__ yt){
  const int c = blockIdx.x;
  const int p = threadIdx.x;
  const int iy = p>>5, ix = p&31;
  __shared__ float plane[18*34];
  for (int i=p;i<18*34;i+=512) plane[i]=0.f;
  float v = bias[c];
  #pragma unroll
  for (int s=0;s<8;s++) v += part[(size_t)s*262144 + c*512 + p];
  v = lrelu_f(v);
  __syncthreads();
  plane[(iy+1)*34 + ix+1] = v;
  __syncthreads();
  const float* kp = kern + c*9;
  float s = 0.f;
  #pragma unroll
  for (int dy=0;dy<3;dy++)
    #pragma unroll
    for (int dx=0;dx<3;dx++)
      s += plane[(iy+dy)*34 + ix+dx]*kp[dy*3+dx];
  yt[(size_t)p*512 + c] = f2bf(lrelu_f(s));
}

// ===== conv 3x3 as MFMA GEMM, direct-staged from XT (no im2col) ==============
// A = WB [512][4608] (k = t*512+ci), B = XT [512 px][512 ch]; split-K=8
#define KCH 576
__global__ __launch_bounds__(256) void k_mfma_conv(
    const unsigned short* __restrict__ WB,
    const unsigned short* __restrict__ XT,
    float* __restrict__ part){
  __shared__ unsigned short lA[2048], lB[2048];
  const int tid = threadIdx.x;
  const int wid = tid>>6, lane = tid&63;
  const int m0 = blockIdx.x*64, n0 = blockIdx.y*64;
  const int k0 = blockIdx.z*KCH;

  const int srow = tid>>2, skb = tid&3;
  const unsigned short* gA = WB + (size_t)(m0+srow)*4608 + k0 + skb*8;
  const int p = n0 + srow, py = p>>5, px = p&31;
  const int soff = srow*32 + 8*(skb ^ (srow&3));

  const int wr = (wid>>1)*32, wc = (wid&1)*32;
  const int l15 = lane&15, lkb = lane>>4;
  int aoff[2], boff[2];
  #pragma unroll
  for (int s=0;s<2;s++){
    const int Ra = wr + s*16 + l15;
    aoff[s] = Ra*32 + 8*(lkb ^ (Ra&3));
    const int Rb = wc + s*16 + l15;
    boff[s] = Rb*32 + 8*(lkb ^ (Rb&3));
  }

  f32x4 acc[2][2] = {};
  for (int kk=0; kk<KCH; kk+=32){
    const int k = k0 + kk;
    const int t = k>>9;                    // 0..8 (32 | 512 so t const per step)
    const int dy = t/3, dx = t - dy*3;
    const int yy = py + dy - 1, xx = px + dx - 1;
    const int ci = (k&511) + skb*8;
    ushort8 rb = {};
    if ((unsigned)yy < 16u && (unsigned)xx < 32u)
      rb = *(const ushort8*)(XT + (size_t)(yy*32+xx)*512 + ci);
    const ushort8 ra = *(const ushort8*)gA;
    gA += 32;
    __syncthreads();
    *(ushort8*)(lA + soff) = ra;
    *(ushort8*)(lB + soff) = rb;
    __syncthreads();
    bf16x8 af[2], bfr[2];
    #pragma unroll
    for (int s=0;s<2;s++){
      af[s]  = *(const bf16x8*)(lA + aoff[s]);
      bfr[s] = *(const bf16x8*)(lB + boff[s]);
    }
    #pragma unroll
    for (int mi=0;mi<2;mi++)
      #pragma unroll
      for (int ni=0;ni<2;ni++)
        acc[mi][ni] = __builtin_amdgcn_mfma_f32_16x16x32_bf16(af[mi], bfr[ni], acc[mi][ni], 0,0,0);
  }

  float* pbase = part + (size_t)blockIdx.z*262144;
  #pragma unroll
  for (int mi=0;mi<2;mi++)
    #pragma unroll
    for (int ni=0;ni<2;ni++){
      const int row = m0 + wr + mi*16 + lkb*4;
      const int col = n0 + wc + ni*16 + l15;
      #pragma unroll
      for (int r=0;r<4;r++)
        pbase[(size_t)(row+r)*512 + col] = acc[mi][ni][r];
    }
}

// ===== final reduce: bias + 8 partials + residual ============================
__global__ __launch_bounds__(256) void k_reduce_final(const float* __restrict__ part,
    const float* __restrict__ bias, const float* __restrict__ res,
    float* __restrict__ y){
  const int idx = blockIdx.x*256 + threadIdx.x;
  const int o = idx>>9;
  float v = bias[o];
  #pragma unroll
  for (int s=0;s<8;s++) v += part[(size_t)s*262144 + idx];
  y[idx] = v + res[idx];
}

extern "C" void kernel_launch(void* const* d_in, const int* in_sizes, int n_in,
                              void* d_out, int out_size, void* d_ws, size_t ws_size,
                              hipStream_t stream) {
  (void)in_sizes; (void)n_in; (void)out_size; (void)ws_size;
  const float* xin    = (const float*)d_in[0];
  const float* deg    = (const float*)d_in[1];
  const float* k1_w1  = (const float*)d_in[2];
  const float* k1_w2  = (const float*)d_in[3];
  const float* p1_w   = (const float*)d_in[4];
  const float* p1_b   = (const float*)d_in[5];
  const float* ca1_w1 = (const float*)d_in[6];
  const float* ca1_w2 = (const float*)d_in[7];
  const float* conv1_w= (const float*)d_in[8];
  const float* conv1_b= (const float*)d_in[9];
  const float* k2_w1  = (const float*)d_in[10];
  const float* k2_w2  = (const float*)d_in[11];
  const float* p2_w   = (const float*)d_in[12];
  const float* p2_b   = (const float*)d_in[13];
  const float* ca2_w1 = (const float*)d_in[14];
  const float* ca2_w2 = (const float*)d_in[15];
  const float* conv2_w= (const float*)d_in[16];
  const float* conv2_b= (const float*)d_in[17];
  float* out = (float*)d_out;

  // ---- workspace (float units) ----
  float* ws = (float*)d_ws;
  float* PART = ws;  ws += 2097152;                 // 8 MB split-K partials
  // aliases into PART: consumed before first k_mfma_conv write
  float* TMP1 = PART;
  float* TMP2 = PART + 262144;
  unsigned short* HID1 = (unsigned short*)(PART + 524288);   // 32768 us
  unsigned short* HID2 = HID1 + 32768;
  float* KERN1 = ws;  ws += 4608;
  float* KERN2 = ws;  ws += 4608;
  float* ATT1  = ws;  ws += 262144;
  float* ATT2  = ws;  ws += 262144;
  unsigned short* DEGB = (unsigned short*)ws; ws += 131072;
  unsigned short* DEGT = (unsigned short*)ws; ws += 131072;
  unsigned short* K1B  = (unsigned short*)ws; ws += 131072;
  unsigned short* K2B  = (unsigned short*)ws; ws += 131072;
  unsigned short* P1B  = (unsigned short*)ws; ws += 131072;
  unsigned short* P2B  = (unsigned short*)ws; ws += 131072;
  unsigned short* CA1A = (unsigned short*)ws; ws += 16384;
  unsigned short* CA1B = (unsigned short*)ws; ws += 16384;
  unsigned short* CA2A = (unsigned short*)ws; ws += 16384;
  unsigned short* CA2B = (unsigned short*)ws; ws += 16384;
  unsigned short* DWLT = (unsigned short*)ws; ws += 131072;
  unsigned short* XT   = (unsigned short*)ws; ws += 131072;  // reused conv1/conv2
  unsigned short* WB1  = (unsigned short*)ws; ws += 1179648;
  unsigned short* WB2  = (unsigned short*)ws; ws += 1179648; // total ~24.4 MB

  // 1. all weight packs (one kernel)
  k_pack_all<<<6272,256,0,stream>>>(k1_w1,k2_w1,p1_w,p2_w,
      ca1_w1,ca1_w2,ca2_w1,ca2_w2, deg, conv1_w, conv2_w,
      K1B,K2B,P1B,P2B, CA1A,CA1B,CA2A,CA2B, DEGB,DEGT, WB1,WB2);

  // 2. TMP{1,2} = lrelu(deg @ kw{1,2}_1^T)   [batched]
  k_mgemm<0><<<dim3(8,8,2),256,0,stream>>>(DEGB,DEGB, K1B,K2B, nullptr,nullptr,nullptr,
      TMP1,TMP2, nullptr,nullptr, 512, 512);
  // 3. KERN{1,2}[i][t] = TMP @ kw2^T          [batched]
  k_kern_gen<<<dim3(512,2),64,0,stream>>>(TMP1,TMP2, k1_w2,k2_w2, KERN1,KERN2);

  // 4. HID{1,2}[px][h] = lrelu(DEGT @ ca_w1^T) [batched, bf16]
  k_mgemm<1><<<dim3(8,1,2),256,0,stream>>>(DEGT,DEGT, CA1A,CA2A, nullptr,nullptr,nullptr,
      nullptr,nullptr, HID1,HID2, 64, 512);
  // 5. ATT{1,2}[c][px] = sigmoid(ca_w2 @ HID^T) [batched]
  k_mgemm<2><<<dim3(8,8,2),256,0,stream>>>(CA1B,CA2B, HID1,HID2, nullptr,nullptr,nullptr,
      ATT1,ATT2, nullptr,nullptr, 512, 64);

  // 6. da_conv1 depthwise -> DWLT [px][ch] bf16
  k_dwconv<<<512,512,0,stream>>>(xin, KERN1, DWLT);
  // 7. pointwise + bias + deg*att + lrelu -> XT [px][ch] bf16
  k_mgemm<4><<<dim3(8,8,1),256,0,stream>>>(P1B,P1B, DWLT,DWLT, p1_b, deg, ATT1,
      nullptr,nullptr, XT,XT, 512, 512);
  // 8. conv1 3x3 (direct-staged implicit GEMM, split-K=8)
  k_mfma_conv<<<dim3(8,8,8),256,0,stream>>>(WB1, XT, PART);
  // 9. fused reduce+lrelu+depthwise (da_conv2) -> DWLT
  k_dwconv_red<<<512,512,0,stream>>>(PART, conv1_b, KERN2, DWLT);
  // 10. pointwise 2 -> XT
  k_mgemm<4><<<dim3(8,8,1),256,0,stream>>>(P2B,P2B, DWLT,DWLT, p2_b, deg, ATT2,
      nullptr,nullptr, XT,XT, 512, 512);
  // 11. conv2 3x3
  k_mfma_conv<<<dim3(8,8,8),256,0,stream>>>(WB2, XT, PART);
  // 12. final reduce + bias + residual
  k_reduce_final<<<1024,256,0,stream>>>(PART, conv2_b, xin, out);
}

// Round 6
// 93.326 us; speedup vs baseline: 5.3834x; 1.1151x over previous
//
#include <hip/hip_runtime.h>
#include <hip/hip_bf16.h>

typedef __attribute__((ext_vector_type(8))) unsigned short ushort8;
typedef __attribute__((ext_vector_type(8))) __bf16 bf16x8;
typedef __attribute__((ext_vector_type(4))) float f32x4;
typedef __attribute__((ext_vector_type(4))) unsigned short ushort4v;

__device__ __forceinline__ float lrelu_f(float v){ return v > 0.f ? v : 0.1f*v; }

__device__ __forceinline__ unsigned short f2bf(float v){
  unsigned u = __float_as_uint(v);
  unsigned r = (u + 0x7fffu + ((u>>16)&1u)) >> 16;
  return (unsigned short)r;
}

__device__ __forceinline__ void packq(const float* __restrict__ s,
                                      unsigned short* __restrict__ d, int i){
  const float4 v = ((const float4*)s)[i];
  ushort4v o; o.x=f2bf(v.x); o.y=f2bf(v.y); o.z=f2bf(v.z); o.w=f2bf(v.w);
  *(ushort4v*)(d + (size_t)i*4) = o;
}

// ============ one fused pack kernel: all weights -> bf16 ============
__global__ __launch_bounds__(256) void k_pack_all(
  const float* __restrict__ k1_w1, const float* __restrict__ k2_w1,
  const float* __restrict__ p1_w,  const float* __restrict__ p2_w,
  const float* __restrict__ ca1_w1,const float* __restrict__ ca1_w2,
  const float* __restrict__ ca2_w1,const float* __restrict__ ca2_w2,
  const float* __restrict__ deg,   const float* __restrict__ conv1_w,
  const float* __restrict__ conv2_w,
  unsigned short* __restrict__ K1B, unsigned short* __restrict__ K2B,
  unsigned short* __restrict__ P1B, unsigned short* __restrict__ P2B,
  unsigned short* __restrict__ CA1A,unsigned short* __restrict__ CA1B,
  unsigned short* __restrict__ CA2A,unsigned short* __restrict__ CA2B,
  unsigned short* __restrict__ DEGB,unsigned short* __restrict__ DEGT,
  unsigned short* __restrict__ WB1, unsigned short* __restrict__ WB2){
  int i = blockIdx.x*256 + threadIdx.x;
  if (i < 65536){ packq(k1_w1, K1B, i); return; } i -= 65536;
  if (i < 65536){ packq(k2_w1, K2B, i); return; } i -= 65536;
  if (i < 65536){ packq(p1_w,  P1B, i); return; } i -= 65536;
  if (i < 65536){ packq(p2_w,  P2B, i); return; } i -= 65536;
  if (i < 8192){ packq(ca1_w1, CA1A, i); return; } i -= 8192;
  if (i < 8192){ packq(ca1_w2, CA1B, i); return; } i -= 8192;
  if (i < 8192){ packq(ca2_w1, CA2A, i); return; } i -= 8192;
  if (i < 8192){ packq(ca2_w2, CA2B, i); return; } i -= 8192;
  if (i < 65536){ packq(deg, DEGB, i); return; } i -= 65536;
  if (i < 65536){                      // DEGT: bf16 transpose of deg
    const int j = i*4; const int p = j>>9, c = j&511;
    ushort4v o;
    o.x = f2bf(deg[(size_t)(c+0)*512 + p]);
    o.y = f2bf(deg[(size_t)(c+1)*512 + p]);
    o.z = f2bf(deg[(size_t)(c+2)*512 + p]);
    o.w = f2bf(deg[(size_t)(c+3)*512 + p]);
    *(ushort4v*)(DEGT + (size_t)j) = o;
    return;
  } i -= 65536;
  if (i < 589824){                     // WB1: [o][t*512+ci] = w[o][ci*9+t]
    const int o_ = i/1152; const int r4 = (i - o_*1152)*4;
    const int t = r4>>9; const int ci = r4&511;
    const float* s = conv1_w + (size_t)o_*4608;
    ushort4v o;
    o.x = f2bf(s[(ci+0)*9 + t]); o.y = f2bf(s[(ci+1)*9 + t]);
    o.z = f2bf(s[(ci+2)*9 + t]); o.w = f2bf(s[(ci+3)*9 + t]);
    *(ushort4v*)(WB1 + (size_t)o_*4608 + r4) = o;
    return;
  } i -= 589824;
  if (i < 589824){                     // WB2
    const int o_ = i/1152; const int r4 = (i - o_*1152)*4;
    const int t = r4>>9; const int ci = r4&511;
    const float* s = conv2_w + (size_t)o_*4608;
    ushort4v o;
    o.x = f2bf(s[(ci+0)*9 + t]); o.y = f2bf(s[(ci+1)*9 + t]);
    o.z = f2bf(s[(ci+2)*9 + t]); o.w = f2bf(s[(ci+3)*9 + t]);
    *(ushort4v*)(WB2 + (size_t)o_*4608 + r4) = o;
  }
}

// ======= shared 64x64 MFMA GEMM core, 4 waves, 2-phase prefetch =======
__device__ __forceinline__ void gemm64(
    const unsigned short* __restrict__ A, const unsigned short* __restrict__ Bt,
    int m0, int n0, int K, int tid,
    unsigned short* lA, unsigned short* lB, f32x4 acc[2][2]){
  const int wid = tid>>6, lane = tid&63;
  const int srow = tid>>2, skb = tid&3;
  const unsigned short* gA = A  + (size_t)(m0+srow)*K + skb*8;
  const unsigned short* gB = Bt + (size_t)(n0+srow)*K + skb*8;
  const int soff = srow*32 + 8*(skb ^ (srow&3));
  const int wr = (wid>>1)*32, wc = (wid&1)*32;
  const int l15 = lane&15, lkb = lane>>4;
  int aoff[2], boff[2];
  #pragma unroll
  for (int s=0;s<2;s++){
    const int Ra = wr + s*16 + l15;
    aoff[s] = Ra*32 + 8*(lkb ^ (Ra&3));
    const int Rb = wc + s*16 + l15;
    boff[s] = Rb*32 + 8*(lkb ^ (Rb&3));
  }
  const int nst = K>>5;
  ushort8 ra = *(const ushort8*)gA;
  ushort8 rb = *(const ushort8*)gB;
  for (int st=0; st<nst; ++st){
    ushort8 ra2 = {}, rb2 = {};
    if (st+1 < nst){
      ra2 = *(const ushort8*)(gA+32);
      rb2 = *(const ushort8*)(gB+32);
    }
    gA += 32; gB += 32;
    __syncthreads();
    *(ushort8*)(lA + soff) = ra;
    *(ushort8*)(lB + soff) = rb;
    __syncthreads();
    bf16x8 af[2], bfr[2];
    #pragma unroll
    for (int s=0;s<2;s++){
      af[s]  = *(const bf16x8*)(lA + aoff[s]);
      bfr[s] = *(const bf16x8*)(lB + boff[s]);
    }
    #pragma unroll
    for (int mi=0;mi<2;mi++)
      #pragma unroll
      for (int ni=0;ni<2;ni++)
        acc[mi][ni] = __builtin_amdgcn_mfma_f32_16x16x32_bf16(af[mi], bfr[ni], acc[mi][ni], 0,0,0);
    ra = ra2; rb = rb2;
  }
}

// ==== batched pre-GEMMs: z=0,1 TMP{1,2}=lrelu(deg@kw1^T) f32 [512][512] ======
//                         z=2,3 HID{1,2}=lrelu(DEGT@ca_w1^T) bf16 [512][64] ===
__global__ __launch_bounds__(256) void k_mgemm_pre(
    const unsigned short* __restrict__ DEGB, const unsigned short* __restrict__ DEGT,
    const unsigned short* __restrict__ K1B,  const unsigned short* __restrict__ K2B,
    const unsigned short* __restrict__ CA1A, const unsigned short* __restrict__ CA2A,
    float* __restrict__ TMP1, float* __restrict__ TMP2,
    unsigned short* __restrict__ HID1, unsigned short* __restrict__ HID2){
  const int z = blockIdx.z;
  if (z >= 2 && blockIdx.y != 0) return;
  const unsigned short* A  = (z < 2) ? DEGB : DEGT;
  const unsigned short* Bt = (z==0) ? K1B : (z==1) ? K2B : (z==2) ? CA1A : CA2A;
  __shared__ unsigned short lA[2048], lB[2048];
  const int tid = threadIdx.x;
  const int m0 = blockIdx.x*64, n0 = blockIdx.y*64;
  f32x4 acc[2][2] = {};
  gemm64(A, Bt, m0, n0, 512, tid, lA, lB, acc);

  const int wid = tid>>6, lane = tid&63;
  const int wr = (wid>>1)*32, wc = (wid&1)*32;
  const int l15 = lane&15, lkb = lane>>4;
  #pragma unroll
  for (int mi=0;mi<2;mi++)
    #pragma unroll
    for (int ni=0;ni<2;ni++){
      const int row = m0 + wr + mi*16 + lkb*4;
      const int col = n0 + wc + ni*16 + l15;
      #pragma unroll
      for (int r=0;r<4;r++){
        const float v = lrelu_f(acc[mi][ni][r]);
        if (z==0)      TMP1[(size_t)(row+r)*512 + col] = v;
        else if (z==1) TMP2[(size_t)(row+r)*512 + col] = v;
        else if (z==2) HID1[(size_t)(row+r)*64 + col] = f2bf(v);
        else           HID2[(size_t)(row+r)*64 + col] = f2bf(v);
      }
    }
}

// ==== batched: z=0,1 kern_gen ; z=2,3 ATT = sigmoid(ca_w2 @ HID^T) ===========
__global__ __launch_bounds__(256) void k_kern_att(
    const float* __restrict__ TMP1, const float* __restrict__ TMP2,
    const float* __restrict__ kw2a, const float* __restrict__ kw2b,
    const unsigned short* __restrict__ CA1B, const unsigned short* __restrict__ CA2B,
    const unsigned short* __restrict__ HID1, const unsigned short* __restrict__ HID2,
    float* __restrict__ kern0, float* __restrict__ kern1,
    float* __restrict__ ATT1, float* __restrict__ ATT2){
  const int z = blockIdx.z;
  const int tid = threadIdx.x;
  if (z < 2){
    // kern[i][t] = sum_j tmp[i][j]*kw2[t][j]; one wave per i, 4 i per block
    const float* tmp  = z ? TMP2 : TMP1;
    const float* kw2  = z ? kw2b : kw2a;
    float* kern       = z ? kern1 : kern0;
    const int i = blockIdx.x*4 + (tid>>6);
    const int lane = tid&63;
    float acc[9];
    #pragma unroll
    for (int q=0;q<9;q++) acc[q]=0.f;
    for (int j=lane; j<512; j+=64){
      const float t = tmp[i*512 + j];
      #pragma unroll
      for (int q=0;q<9;q++) acc[q] += t*kw2[q*512 + j];
    }
    #pragma unroll
    for (int q=0;q<9;q++){
      float v = acc[q];
      #pragma unroll
      for (int off=32; off>0; off>>=1) v += __shfl_down(v, off);
      if (lane==0) kern[i*9+q] = v;
    }
  } else {
    if (blockIdx.x >= 64) return;
    const unsigned short* A  = (z==2) ? CA1B : CA2B;   // [512][64]
    const unsigned short* Bt = (z==2) ? HID1 : HID2;   // [512][64]
    float* ATT               = (z==2) ? ATT1 : ATT2;
    __shared__ unsigned short lA[2048], lB[2048];
    const int m0 = (blockIdx.x>>3)*64, n0 = (blockIdx.x&7)*64;
    f32x4 acc[2][2] = {};
    gemm64(A, Bt, m0, n0, 64, tid, lA, lB, acc);
    const int wid = tid>>6, lane = tid&63;
    const int wr = (wid>>1)*32, wc = (wid&1)*32;
    const int l15 = lane&15, lkb = lane>>4;
    #pragma unroll
    for (int mi=0;mi<2;mi++)
      #pragma unroll
      for (int ni=0;ni<2;ni++){
        const int row = m0 + wr + mi*16 + lkb*4;
        const int col = n0 + wc + ni*16 + l15;
        #pragma unroll
        for (int r=0;r<4;r++)
          ATT[(size_t)(row+r)*512 + col] = 1.f/(1.f + expf(-acc[mi][ni][r]));
      }
  }
}

// ==== depthwise 3x3 (SAME) + lrelu, f32 input, OUT transposed bf16 [px][ch] ===
__global__ __launch_bounds__(512) void k_dwconv(const float* __restrict__ x,
    const float* __restrict__ kern, unsigned short* __restrict__ yt){
  const int c = blockIdx.x;
  const int p = threadIdx.x;
  const int iy = p>>5, ix = p&31;
  __shared__ float plane[18*34];
  for (int i=p;i<18*34;i+=512) plane[i]=0.f;
  __syncthreads();
  plane[(iy+1)*34 + ix+1] = x[c*512 + p];
  __syncthreads();
  const float* kp = kern + c*9;
  float s = 0.f;
  #pragma unroll
  for (int dy=0;dy<3;dy++)
    #pragma unroll
    for (int dx=0;dx<3;dx++)
      s += plane[(iy+dy)*34 + ix+dx]*kp[dy*3+dx];
  yt[(size_t)p*512 + c] = f2bf(lrelu_f(s));
}

// ==== fused: reduce nchunks partials + bias + lrelu, then depthwise -> yt ====
__global__ __launch_bounds__(512) void k_dwconv_red(const float* __restrict__ part,
    const float* __restrict__ bias, const float* __restrict__ kern,
    unsigned short* __restrict__ yt, int nchunks){
  const int c = blockIdx.x;
  const int p = threadIdx.x;
  const int iy = p>>5, ix = p&31;
  __shared__ float plane[18*34];
  for (int i=p;i<18*34;i+=512) plane[i]=0.f;
  float v = bias[c];
  for (int s=0;s<nchunks;s++) v += part[(size_t)s*262144 + c*512 + p];
  v = lrelu_f(v);
  __syncthreads();
  plane[(iy+1)*34 + ix+1] = v;
  __syncthreads();
  const float* kp = kern + c*9;
  float s = 0.f;
  #pragma unroll
  for (int dy=0;dy<3;dy++)
    #pragma unroll
    for (int dx=0;dx<3;dx++)
      s += plane[(iy+dy)*34 + ix+dx]*kp[dy*3+dx];
  yt[(size_t)p*512 + c] = f2bf(lrelu_f(s));
}

// ==== pointwise GEMM 32x32-tile: X[c][p]=lrelu(bias+sum p_w*DWL + deg*att) ===
// A [512 ch][512 k] bf16; Bt = DWLT [512 px][512 k] bf16; out XT [px][ch] bf16
__global__ __launch_bounds__(256) void k_pw(
    const unsigned short* __restrict__ A, const unsigned short* __restrict__ Bt,
    const float* __restrict__ bias,
    const float* __restrict__ E1, const float* __restrict__ E2,
    unsigned short* __restrict__ XT){
  __shared__ unsigned short lA[1024], lB[1024];
  __shared__ float tile[32][33];
  const int tid = threadIdx.x;
  const int wid = tid>>6, lane = tid&63;
  const int M0 = blockIdx.x*32, N0 = blockIdx.y*32;

  const int half = tid>>7;                 // 0: stage A, 1: stage B
  const int st_ = tid&127;
  const int srow = st_>>2, skb = st_&3;
  const unsigned short* gS = (half ? Bt + (size_t)(N0+srow)*512
                                   : A  + (size_t)(M0+srow)*512) + skb*8;
  unsigned short* lS = (half ? lB : lA);
  const int soff = srow*32 + 8*(skb ^ (srow&3));

  const int wr = (wid>>1)*16, wc = (wid&1)*16;
  const int l15 = lane&15, lkb = lane>>4;
  const int Ra = wr + l15, Rb = wc + l15;
  const int aoff = Ra*32 + 8*(lkb ^ (Ra&3));
  const int boff = Rb*32 + 8*(lkb ^ (Rb&3));

  f32x4 acc = {};
  ushort8 r0 = *(const ushort8*)gS;
  #pragma unroll 1
  for (int st=0; st<16; ++st){
    ushort8 r1 = {};
    if (st < 15) r1 = *(const ushort8*)(gS+32);
    gS += 32;
    __syncthreads();
    *(ushort8*)(lS + soff) = r0;
    __syncthreads();
    const bf16x8 af = *(const bf16x8*)(lA + aoff);
    const bf16x8 bf = *(const bf16x8*)(lB + boff);
    acc = __builtin_amdgcn_mfma_f32_16x16x32_bf16(af, bf, acc, 0,0,0);
    r0 = r1;
  }

  #pragma unroll
  for (int r=0;r<4;r++){
    const int rl = wr + lkb*4 + r;         // channel within tile
    const int cl = wc + l15;               // pixel within tile
    const int rr = M0 + rl, col = N0 + cl;
    float v = acc[r] + bias[rr] + E1[(size_t)rr*512+col]*E2[(size_t)rr*512+col];
    tile[rl][cl] = lrelu_f(v);
  }
  __syncthreads();
  const int pr = tid>>3, q = tid&7;        // pixel row, channel quad
  ushort4v o;
  o.x = f2bf(tile[q*4+0][pr]); o.y = f2bf(tile[q*4+1][pr]);
  o.z = f2bf(tile[q*4+2][pr]); o.w = f2bf(tile[q*4+3][pr]);
  *(ushort4v*)(XT + (size_t)(N0+pr)*512 + M0 + q*4) = o;
}

// ===== conv 3x3 as MFMA GEMM, direct-staged from XT (no im2col) ==============
// A = WB [512][4608] (k = t*512+ci), B = XT [512 px][512 ch]; split-K template
template<int KCH>
__global__ __launch_bounds__(256) void k_mfma_conv(
    const unsigned short* __restrict__ WB,
    const unsigned short* __restrict__ XT,
    float* __restrict__ part){
  __shared__ unsigned short lA[2048], lB[2048];
  const int tid = threadIdx.x;
  const int wid = tid>>6, lane = tid&63;
  const int m0 = blockIdx.x*64, n0 = blockIdx.y*64;
  const int k0 = blockIdx.z*KCH;

  const int srow = tid>>2, skb = tid&3;
  const unsigned short* gA = WB + (size_t)(m0+srow)*4608 + k0 + skb*8;
  const int p = n0 + srow, py = p>>5, px = p&31;
  const int soff = srow*32 + 8*(skb ^ (srow&3));

  const int wr = (wid>>1)*32, wc = (wid&1)*32;
  const int l15 = lane&15, lkb = lane>>4;
  int aoff[2], boff[2];
  #pragma unroll
  for (int s=0;s<2;s++){
    const int Ra = wr + s*16 + l15;
    aoff[s] = Ra*32 + 8*(lkb ^ (Ra&3));
    const int Rb = wc + s*16 + l15;
    boff[s] = Rb*32 + 8*(lkb ^ (Rb&3));
  }

  auto loadB = [&](int step)->ushort8 {
    const int k = k0 + step*32;
    const int t = k>>9;
    const int dy = t/3, dx = t - dy*3;
    const int yy = py + dy - 1, xx = px + dx - 1;
    ushort8 r = {};
    if ((unsigned)yy < 16u && (unsigned)xx < 32u)
      r = *(const ushort8*)(XT + (size_t)(yy*32+xx)*512 + (k&511) + skb*8);
    return r;
  };

  constexpr int NST = KCH/32;
  f32x4 acc[2][2] = {};
  ushort8 ra = *(const ushort8*)gA;
  ushort8 rb = loadB(0);
  #pragma unroll 1
  for (int st=0; st<NST; ++st){
    ushort8 ra2 = {}, rb2 = {};
    if (st+1 < NST){
      ra2 = *(const ushort8*)(gA+32);
      rb2 = loadB(st+1);
    }
    gA += 32;
    __syncthreads();
    *(ushort8*)(lA + soff) = ra;
    *(ushort8*)(lB + soff) = rb;
    __syncthreads();
    bf16x8 af[2], bfr[2];
    #pragma unroll
    for (int s=0;s<2;s++){
      af[s]  = *(const bf16x8*)(lA + aoff[s]);
      bfr[s] = *(const bf16x8*)(lB + boff[s]);
    }
    #pragma unroll
    for (int mi=0;mi<2;mi++)
      #pragma unroll
      for (int ni=0;ni<2;ni++)
        acc[mi][ni] = __builtin_amdgcn_mfma_f32_16x16x32_bf16(af[mi], bfr[ni], acc[mi][ni], 0,0,0);
    ra = ra2; rb = rb2;
  }

  float* pbase = part + (size_t)blockIdx.z*262144;
  #pragma unroll
  for (int mi=0;mi<2;mi++)
    #pragma unroll
    for (int ni=0;ni<2;ni++){
      const int row = m0 + wr + mi*16 + lkb*4;
      const int col = n0 + wc + ni*16 + l15;
      #pragma unroll
      for (int r=0;r<4;r++)
        pbase[(size_t)(row+r)*512 + col] = acc[mi][ni][r];
    }
}

// ===== final reduce: bias + partials + residual ==============================
__global__ __launch_bounds__(256) void k_reduce_final(const float* __restrict__ part,
    const float* __restrict__ bias, const float* __restrict__ res,
    float* __restrict__ y, int nchunks){
  const int idx = blockIdx.x*256 + threadIdx.x;
  const int o = idx>>9;
  float v = bias[o];
  for (int s=0;s<nchunks;s++) v += part[(size_t)s*262144 + idx];
  y[idx] = v + res[idx];
}

extern "C" void kernel_launch(void* const* d_in, const int* in_sizes, int n_in,
                              void* d_out, int out_size, void* d_ws, size_t ws_size,
                              hipStream_t stream) {
  (void)in_sizes; (void)n_in; (void)out_size;
  const float* xin    = (const float*)d_in[0];
  const float* deg    = (const float*)d_in[1];
  const float* k1_w1  = (const float*)d_in[2];
  const float* k1_w2  = (const float*)d_in[3];
  const float* p1_w   = (const float*)d_in[4];
  const float* p1_b   = (const float*)d_in[5];
  const float* ca1_w1 = (const float*)d_in[6];
  const float* ca1_w2 = (const float*)d_in[7];
  const float* conv1_w= (const float*)d_in[8];
  const float* conv1_b= (const float*)d_in[9];
  const float* k2_w1  = (const float*)d_in[10];
  const float* k2_w2  = (const float*)d_in[11];
  const float* p2_w   = (const float*)d_in[12];
  const float* p2_b   = (const float*)d_in[13];
  const float* ca2_w1 = (const float*)d_in[14];
  const float* ca2_w2 = (const float*)d_in[15];
  const float* conv2_w= (const float*)d_in[16];
  const float* conv2_b= (const float*)d_in[17];
  float* out = (float*)d_out;

  // split-K for conv: 16 if workspace allows (adds 8 MB), else 8
  const bool big = ws_size >= (size_t)8202000*4;
  const int NS = big ? 16 : 8;

  // ---- workspace (float units) ----
  float* ws = (float*)d_ws;
  float* PART = ws;  ws += (size_t)NS*262144;
  // aliases into PART: consumed before first k_mfma_conv write
  float* TMP1 = PART;
  float* TMP2 = PART + 262144;
  unsigned short* HID1 = (unsigned short*)(PART + 524288);   // 32768 us
  unsigned short* HID2 = HID1 + 32768;
  float* KERN1 = ws;  ws += 4608;
  float* KERN2 = ws;  ws += 4608;
  float* ATT1  = ws;  ws += 262144;
  float* ATT2  = ws;  ws += 262144;
  unsigned short* DEGB = (unsigned short*)ws; ws += 131072;
  unsigned short* DEGT = (unsigned short*)ws; ws += 131072;
  unsigned short* K1B  = (unsigned short*)ws; ws += 131072;
  unsigned short* K2B  = (unsigned short*)ws; ws += 131072;
  unsigned short* P1B  = (unsigned short*)ws; ws += 131072;
  unsigned short* P2B  = (unsigned short*)ws; ws += 131072;
  unsigned short* CA1A = (unsigned short*)ws; ws += 16384;
  unsigned short* CA1B = (unsigned short*)ws; ws += 16384;
  unsigned short* CA2A = (unsigned short*)ws; ws += 16384;
  unsigned short* CA2B = (unsigned short*)ws; ws += 16384;
  unsigned short* DWLT = (unsigned short*)ws; ws += 131072;
  unsigned short* XT   = (unsigned short*)ws; ws += 131072;
  unsigned short* WB1  = (unsigned short*)ws; ws += 1179648;
  unsigned short* WB2  = (unsigned short*)ws; ws += 1179648;

  // 1. all weight packs
  k_pack_all<<<6272,256,0,stream>>>(k1_w1,k2_w1,p1_w,p2_w,
      ca1_w1,ca1_w2,ca2_w1,ca2_w2, deg, conv1_w, conv2_w,
      K1B,K2B,P1B,P2B, CA1A,CA1B,CA2A,CA2B, DEGB,DEGT, WB1,WB2);

  // 2. TMP{1,2} + HID{1,2}   [z-batched]
  k_mgemm_pre<<<dim3(8,8,4),256,0,stream>>>(DEGB,DEGT, K1B,K2B, CA1A,CA2A,
      TMP1,TMP2, HID1,HID2);
  // 3. KERN{1,2} + ATT{1,2}  [z-batched]
  k_kern_att<<<dim3(128,1,4),256,0,stream>>>(TMP1,TMP2, k1_w2,k2_w2,
      CA1B,CA2B, HID1,HID2, KERN1,KERN2, ATT1,ATT2);

  // 4. da_conv1 depthwise -> DWLT [px][ch] bf16
  k_dwconv<<<512,512,0,stream>>>(xin, KERN1, DWLT);
  // 5. pointwise 1 (+bias+deg*att+lrelu) -> XT
  k_pw<<<dim3(16,16),256,0,stream>>>(P1B, DWLT, p1_b, deg, ATT1, XT);
  // 6. conv1 3x3 (direct-staged implicit GEMM)
  if (big) k_mfma_conv<288><<<dim3(8,8,16),256,0,stream>>>(WB1, XT, PART);
  else     k_mfma_conv<576><<<dim3(8,8,8), 256,0,stream>>>(WB1, XT, PART);
  // 7. fused reduce+lrelu+depthwise (da_conv2) -> DWLT
  k_dwconv_red<<<512,512,0,stream>>>(PART, conv1_b, KERN2, DWLT, NS);
  // 8. pointwise 2 -> XT
  k_pw<<<dim3(16,16),256,0,stream>>>(P2B, DWLT, p2_b, deg, ATT2, XT);
  // 9. conv2 3x3
  if (big) k_mfma_conv<288><<<dim3(8,8,16),256,0,stream>>>(WB2, XT, PART);
  else     k_mfma_conv<576><<<dim3(8,8,8), 256,0,stream>>>(WB2, XT, PART);
  // 10. final reduce + bias + residual
  k_reduce_final<<<1024,256,0,stream>>>(PART, conv2_b, xin, out, NS);
}

// Round 7
// 87.915 us; speedup vs baseline: 5.7147x; 1.0615x over previous
//
#include <hip/hip_runtime.h>
#include <hip/hip_bf16.h>

typedef __attribute__((ext_vector_type(8))) unsigned short ushort8;
typedef __attribute__((ext_vector_type(8))) __bf16 bf16x8;
typedef __attribute__((ext_vector_type(4))) float f32x4;
typedef __attribute__((ext_vector_type(4))) unsigned short ushort4v;

__device__ __forceinline__ float lrelu_f(float v){ return v > 0.f ? v : 0.1f*v; }

__device__ __forceinline__ unsigned short f2bf(float v){
  unsigned u = __float_as_uint(v);
  unsigned r = (u + 0x7fffu + ((u>>16)&1u)) >> 16;
  return (unsigned short)r;
}

__device__ __forceinline__ void packq(const float* __restrict__ s,
                                      unsigned short* __restrict__ d, int i){
  const float4 v = ((const float4*)s)[i];
  ushort4v o; o.x=f2bf(v.x); o.y=f2bf(v.y); o.z=f2bf(v.z); o.w=f2bf(v.w);
  *(ushort4v*)(d + (size_t)i*4) = o;
}

// ============ one fused pack kernel: all weights -> bf16 ============
__global__ __launch_bounds__(256) void k_pack_all(
  const float* __restrict__ k1_w1, const float* __restrict__ k2_w1,
  const float* __restrict__ p1_w,  const float* __restrict__ p2_w,
  const float* __restrict__ ca1_w1,const float* __restrict__ ca1_w2,
  const float* __restrict__ ca2_w1,const float* __restrict__ ca2_w2,
  const float* __restrict__ deg,   const float* __restrict__ conv1_w,
  const float* __restrict__ conv2_w,
  unsigned short* __restrict__ K1B, unsigned short* __restrict__ K2B,
  unsigned short* __restrict__ P1B, unsigned short* __restrict__ P2B,
  unsigned short* __restrict__ CA1A,unsigned short* __restrict__ CA1B,
  unsigned short* __restrict__ CA2A,unsigned short* __restrict__ CA2B,
  unsigned short* __restrict__ DEGB,unsigned short* __restrict__ DEGT,
  unsigned short* __restrict__ WB1, unsigned short* __restrict__ WB2){
  int i = blockIdx.x*256 + threadIdx.x;
  if (i < 65536){ packq(k1_w1, K1B, i); return; } i -= 65536;
  if (i < 65536){ packq(k2_w1, K2B, i); return; } i -= 65536;
  if (i < 65536){ packq(p1_w,  P1B, i); return; } i -= 65536;
  if (i < 65536){ packq(p2_w,  P2B, i); return; } i -= 65536;
  if (i < 8192){ packq(ca1_w1, CA1A, i); return; } i -= 8192;
  if (i < 8192){ packq(ca1_w2, CA1B, i); return; } i -= 8192;
  if (i < 8192){ packq(ca2_w1, CA2A, i); return; } i -= 8192;
  if (i < 8192){ packq(ca2_w2, CA2B, i); return; } i -= 8192;
  if (i < 65536){ packq(deg, DEGB, i); return; } i -= 65536;
  if (i < 65536){                      // DEGT: bf16 transpose of deg
    const int j = i*4; const int p = j>>9, c = j&511;
    ushort4v o;
    o.x = f2bf(deg[(size_t)(c+0)*512 + p]);
    o.y = f2bf(deg[(size_t)(c+1)*512 + p]);
    o.z = f2bf(deg[(size_t)(c+2)*512 + p]);
    o.w = f2bf(deg[(size_t)(c+3)*512 + p]);
    *(ushort4v*)(DEGT + (size_t)j) = o;
    return;
  } i -= 65536;
  if (i < 589824){                     // WB1: [o][t*512+ci] = w[o][ci*9+t]
    const int o_ = i/1152; const int r4 = (i - o_*1152)*4;
    const int t = r4>>9; const int ci = r4&511;
    const float* s = conv1_w + (size_t)o_*4608;
    ushort4v o;
    o.x = f2bf(s[(ci+0)*9 + t]); o.y = f2bf(s[(ci+1)*9 + t]);
    o.z = f2bf(s[(ci+2)*9 + t]); o.w = f2bf(s[(ci+3)*9 + t]);
    *(ushort4v*)(WB1 + (size_t)o_*4608 + r4) = o;
    return;
  } i -= 589824;
  if (i < 589824){                     // WB2
    const int o_ = i/1152; const int r4 = (i - o_*1152)*4;
    const int t = r4>>9; const int ci = r4&511;
    const float* s = conv2_w + (size_t)o_*4608;
    ushort4v o;
    o.x = f2bf(s[(ci+0)*9 + t]); o.y = f2bf(s[(ci+1)*9 + t]);
    o.z = f2bf(s[(ci+2)*9 + t]); o.w = f2bf(s[(ci+3)*9 + t]);
    *(ushort4v*)(WB2 + (size_t)o_*4608 + r4) = o;
  }
}

// ======= shared 64x64 MFMA GEMM core, 4 waves, dbuf single-barrier =======
// lA/lB are [2][2048] ushort flattened (stride 2048)
__device__ __forceinline__ void gemm64(
    const unsigned short* __restrict__ A, const unsigned short* __restrict__ Bt,
    int m0, int n0, int K, int tid,
    unsigned short* lA, unsigned short* lB, f32x4 acc[2][2]){
  const int wid = tid>>6, lane = tid&63;
  const int srow = tid>>2, skb = tid&3;
  const unsigned short* gA = A  + (size_t)(m0+srow)*K + skb*8;
  const unsigned short* gB = Bt + (size_t)(n0+srow)*K + skb*8;
  const int soff = srow*32 + 8*(skb ^ (srow&3));
  const int wr = (wid>>1)*32, wc = (wid&1)*32;
  const int l15 = lane&15, lkb = lane>>4;
  int aoff[2], boff[2];
  #pragma unroll
  for (int s=0;s<2;s++){
    const int Ra = wr + s*16 + l15;
    aoff[s] = Ra*32 + 8*(lkb ^ (Ra&3));
    const int Rb = wc + s*16 + l15;
    boff[s] = Rb*32 + 8*(lkb ^ (Rb&3));
  }
  const int nst = K>>5;
  ushort8 ra = *(const ushort8*)gA;
  ushort8 rb = *(const ushort8*)gB;
  *(ushort8*)(lA + soff) = ra;
  *(ushort8*)(lB + soff) = rb;
  if (nst > 1){ ra = *(const ushort8*)(gA+32); rb = *(const ushort8*)(gB+32); }
  __syncthreads();
  for (int st=0; st<nst; ++st){
    const int cur = (st&1)*2048;
    bf16x8 af[2], bfr[2];
    #pragma unroll
    for (int s=0;s<2;s++){
      af[s]  = *(const bf16x8*)(lA + cur + aoff[s]);
      bfr[s] = *(const bf16x8*)(lB + cur + boff[s]);
    }
    if (st+1 < nst){
      const int nxt = ((st+1)&1)*2048;
      *(ushort8*)(lA + nxt + soff) = ra;
      *(ushort8*)(lB + nxt + soff) = rb;
      if (st+2 < nst){
        ra = *(const ushort8*)(gA + (size_t)(st+2)*32);
        rb = *(const ushort8*)(gB + (size_t)(st+2)*32);
      }
    }
    #pragma unroll
    for (int mi=0;mi<2;mi++)
      #pragma unroll
      for (int ni=0;ni<2;ni++)
        acc[mi][ni] = __builtin_amdgcn_mfma_f32_16x16x32_bf16(af[mi], bfr[ni], acc[mi][ni], 0,0,0);
    __syncthreads();
  }
}

// ==== batched pre-GEMMs: z=0,1 TMP{1,2}=lrelu(deg@kw1^T) f32 [512][512] ======
//                         z=2,3 HID{1,2}=lrelu(DEGT@ca_w1^T) bf16 [512][64] ===
__global__ __launch_bounds__(256) void k_mgemm_pre(
    const unsigned short* __restrict__ DEGB, const unsigned short* __restrict__ DEGT,
    const unsigned short* __restrict__ K1B,  const unsigned short* __restrict__ K2B,
    const unsigned short* __restrict__ CA1A, const unsigned short* __restrict__ CA2A,
    float* __restrict__ TMP1, float* __restrict__ TMP2,
    unsigned short* __restrict__ HID1, unsigned short* __restrict__ HID2){
  const int z = blockIdx.z;
  if (z >= 2 && blockIdx.y != 0) return;
  const unsigned short* A  = (z < 2) ? DEGB : DEGT;
  const unsigned short* Bt = (z==0) ? K1B : (z==1) ? K2B : (z==2) ? CA1A : CA2A;
  __shared__ unsigned short lA[4096], lB[4096];
  const int tid = threadIdx.x;
  const int m0 = blockIdx.x*64, n0 = blockIdx.y*64;
  f32x4 acc[2][2] = {};
  gemm64(A, Bt, m0, n0, 512, tid, lA, lB, acc);

  const int wid = tid>>6, lane = tid&63;
  const int wr = (wid>>1)*32, wc = (wid&1)*32;
  const int l15 = lane&15, lkb = lane>>4;
  #pragma unroll
  for (int mi=0;mi<2;mi++)
    #pragma unroll
    for (int ni=0;ni<2;ni++){
      const int row = m0 + wr + mi*16 + lkb*4;
      const int col = n0 + wc + ni*16 + l15;
      #pragma unroll
      for (int r=0;r<4;r++){
        const float v = lrelu_f(acc[mi][ni][r]);
        if (z==0)      TMP1[(size_t)(row+r)*512 + col] = v;
        else if (z==1) TMP2[(size_t)(row+r)*512 + col] = v;
        else if (z==2) HID1[(size_t)(row+r)*64 + col] = f2bf(v);
        else           HID2[(size_t)(row+r)*64 + col] = f2bf(v);
      }
    }
}

// ==== batched: z=0,1 kern_gen ; z=2,3 ATT = sigmoid(ca_w2 @ HID^T) ===========
__global__ __launch_bounds__(256) void k_kern_att(
    const float* __restrict__ TMP1, const float* __restrict__ TMP2,
    const float* __restrict__ kw2a, const float* __restrict__ kw2b,
    const unsigned short* __restrict__ CA1B, const unsigned short* __restrict__ CA2B,
    const unsigned short* __restrict__ HID1, const unsigned short* __restrict__ HID2,
    float* __restrict__ kern0, float* __restrict__ kern1,
    float* __restrict__ ATT1, float* __restrict__ ATT2){
  const int z = blockIdx.z;
  const int tid = threadIdx.x;
  if (z < 2){
    const float* tmp  = z ? TMP2 : TMP1;
    const float* kw2  = z ? kw2b : kw2a;
    float* kern       = z ? kern1 : kern0;
    const int i = blockIdx.x*4 + (tid>>6);
    const int lane = tid&63;
    float acc[9];
    #pragma unroll
    for (int q=0;q<9;q++) acc[q]=0.f;
    for (int j=lane; j<512; j+=64){
      const float t = tmp[i*512 + j];
      #pragma unroll
      for (int q=0;q<9;q++) acc[q] += t*kw2[q*512 + j];
    }
    #pragma unroll
    for (int q=0;q<9;q++){
      float v = acc[q];
      #pragma unroll
      for (int off=32; off>0; off>>=1) v += __shfl_down(v, off);
      if (lane==0) kern[i*9+q] = v;
    }
  } else {
    if (blockIdx.x >= 64) return;
    const unsigned short* A  = (z==2) ? CA1B : CA2B;   // [512][64]
    const unsigned short* Bt = (z==2) ? HID1 : HID2;   // [512][64]
    float* ATT               = (z==2) ? ATT1 : ATT2;
    __shared__ unsigned short lA[4096], lB[4096];
    const int m0 = (blockIdx.x>>3)*64, n0 = (blockIdx.x&7)*64;
    f32x4 acc[2][2] = {};
    gemm64(A, Bt, m0, n0, 64, tid, lA, lB, acc);
    const int wid = tid>>6, lane = tid&63;
    const int wr = (wid>>1)*32, wc = (wid&1)*32;
    const int l15 = lane&15, lkb = lane>>4;
    #pragma unroll
    for (int mi=0;mi<2;mi++)
      #pragma unroll
      for (int ni=0;ni<2;ni++){
        const int row = m0 + wr + mi*16 + lkb*4;
        const int col = n0 + wc + ni*16 + l15;
        #pragma unroll
        for (int r=0;r<4;r++)
          ATT[(size_t)(row+r)*512 + col] = 1.f/(1.f + expf(-acc[mi][ni][r]));
      }
  }
}

// ==== depthwise 3x3 (SAME) + lrelu, f32 input, OUT transposed bf16 [px][ch] ===
__global__ __launch_bounds__(512) void k_dwconv(const float* __restrict__ x,
    const float* __restrict__ kern, unsigned short* __restrict__ yt){
  const int c = blockIdx.x;
  const int p = threadIdx.x;
  const int iy = p>>5, ix = p&31;
  __shared__ float plane[18*34];
  for (int i=p;i<18*34;i+=512) plane[i]=0.f;
  __syncthreads();
  plane[(iy+1)*34 + ix+1] = x[c*512 + p];
  __syncthreads();
  const float* kp = kern + c*9;
  float s = 0.f;
  #pragma unroll
  for (int dy=0;dy<3;dy++)
    #pragma unroll
    for (int dx=0;dx<3;dx++)
      s += plane[(iy+dy)*34 + ix+dx]*kp[dy*3+dx];
  yt[(size_t)p*512 + c] = f2bf(lrelu_f(s));
}

// ==== fused: reduce nchunks partials (float4) + bias + lrelu, then dw -> yt ===
__global__ __launch_bounds__(512) void k_dwconv_red(const float* __restrict__ part,
    const float* __restrict__ bias, const float* __restrict__ kern,
    unsigned short* __restrict__ yt, int nchunks){
  const int c = blockIdx.x;
  const int p = threadIdx.x;
  const int iy = p>>5, ix = p&31;
  __shared__ float plane[18*34];
  for (int i=p;i<18*34;i+=512) plane[i]=0.f;
  __syncthreads();
  if (p < 128){
    const float b = bias[c];
    float4 a4 = {b,b,b,b};
    for (int s=0;s<nchunks;s++){
      const float4 v = ((const float4*)(part + (size_t)s*262144 + c*512))[p];
      a4.x += v.x; a4.y += v.y; a4.z += v.z; a4.w += v.w;
    }
    a4.x = lrelu_f(a4.x); a4.y = lrelu_f(a4.y);
    a4.z = lrelu_f(a4.z); a4.w = lrelu_f(a4.w);
    const int px0 = p*4;
    float* dst = &plane[((px0>>5)+1)*34 + (px0&31)+1];
    dst[0]=a4.x; dst[1]=a4.y; dst[2]=a4.z; dst[3]=a4.w;
  }
  __syncthreads();
  const float* kp = kern + c*9;
  float s = 0.f;
  #pragma unroll
  for (int dy=0;dy<3;dy++)
    #pragma unroll
    for (int dx=0;dx<3;dx++)
      s += plane[(iy+dy)*34 + ix+dx]*kp[dy*3+dx];
  yt[(size_t)p*512 + c] = f2bf(lrelu_f(s));
}

// ==== pointwise GEMM 32x32-tile, dbuf single-barrier ====
// A [512 ch][512 k] bf16; Bt = DWLT [512 px][512 k] bf16; out XT [px][ch] bf16
__global__ __launch_bounds__(256) void k_pw(
    const unsigned short* __restrict__ A, const unsigned short* __restrict__ Bt,
    const float* __restrict__ bias,
    const float* __restrict__ E1, const float* __restrict__ E2,
    unsigned short* __restrict__ XT){
  __shared__ unsigned short lA[2][1024], lB[2][1024];
  __shared__ float tile[32][33];
  const int tid = threadIdx.x;
  const int wid = tid>>6, lane = tid&63;
  const int M0 = blockIdx.x*32, N0 = blockIdx.y*32;

  const int half = tid>>7;                 // 0: stage A, 1: stage B
  const int st_ = tid&127;
  const int srow = st_>>2, skb = st_&3;
  const unsigned short* gS = (half ? Bt + (size_t)(N0+srow)*512
                                   : A  + (size_t)(M0+srow)*512) + skb*8;
  unsigned short (*lS)[1024] = half ? lB : lA;
  const int soff = srow*32 + 8*(skb ^ (srow&3));

  const int wr = (wid>>1)*16, wc = (wid&1)*16;
  const int l15 = lane&15, lkb = lane>>4;
  const int Ra = wr + l15, Rb = wc + l15;
  const int aoff = Ra*32 + 8*(lkb ^ (Ra&3));
  const int boff = Rb*32 + 8*(lkb ^ (Rb&3));

  f32x4 acc = {};
  ushort8 r0 = *(const ushort8*)gS;
  *(ushort8*)(&lS[0][soff]) = r0;
  r0 = *(const ushort8*)(gS+32);
  __syncthreads();
  for (int st=0; st<16; ++st){
    const int cur = st&1;
    const bf16x8 af = *(const bf16x8*)(&lA[cur][aoff]);
    const bf16x8 bf = *(const bf16x8*)(&lB[cur][boff]);
    if (st+1 < 16){
      *(ushort8*)(&lS[cur^1][soff]) = r0;
      if (st+2 < 16) r0 = *(const ushort8*)(gS + (size_t)(st+2)*32);
    }
    acc = __builtin_amdgcn_mfma_f32_16x16x32_bf16(af, bf, acc, 0,0,0);
    __syncthreads();
  }

  #pragma unroll
  for (int r=0;r<4;r++){
    const int rl = wr + lkb*4 + r;         // channel within tile
    const int cl = wc + l15;               // pixel within tile
    const int rr = M0 + rl, col = N0 + cl;
    float v = acc[r] + bias[rr] + E1[(size_t)rr*512+col]*E2[(size_t)rr*512+col];
    tile[rl][cl] = lrelu_f(v);
  }
  __syncthreads();
  const int pr = tid>>3, q = tid&7;        // pixel row, channel quad
  ushort4v o;
  o.x = f2bf(tile[q*4+0][pr]); o.y = f2bf(tile[q*4+1][pr]);
  o.z = f2bf(tile[q*4+2][pr]); o.w = f2bf(tile[q*4+3][pr]);
  *(ushort4v*)(XT + (size_t)(N0+pr)*512 + M0 + q*4) = o;
}

// ===== conv 3x3 as MFMA GEMM 64x128 tile, direct-staged, dbuf 1-barrier ======
// A = WB [512][4608] (k = t*512+ci), B = XT [512 px][512 ch]; grid (8,4,NS)
template<int KCH>
__global__ __launch_bounds__(256) void k_mfma_conv(
    const unsigned short* __restrict__ WB,
    const unsigned short* __restrict__ XT,
    float* __restrict__ part){
  __shared__ unsigned short lA[2][2048], lB[2][4096];
  const int tid = threadIdx.x;
  const int wid = tid>>6, lane = tid&63;
  const int m0 = blockIdx.x*64, n0 = blockIdx.y*128;
  const int k0 = blockIdx.z*KCH;

  const int srow = tid>>2, skb = tid&3;
  const unsigned short* gA = WB + (size_t)(m0+srow)*4608 + k0 + skb*8;
  const int soffA = srow*32 + 8*(skb ^ (srow&3));
  const int brow1 = srow + 64;
  const int p0 = n0 + srow, p1 = n0 + brow1;
  const int py0 = p0>>5, px0 = p0&31, py1 = p1>>5, px1 = p1&31;
  const int soffB0 = srow*32 + 8*(skb ^ (srow&3));
  const int soffB1 = brow1*32 + 8*(skb ^ (brow1&3));

  const int wr = (wid>>1)*32, wc = (wid&1)*64;
  const int l15 = lane&15, lkb = lane>>4;
  int aoff[2], boff[4];
  #pragma unroll
  for (int s=0;s<2;s++){
    const int Ra = wr + s*16 + l15;
    aoff[s] = Ra*32 + 8*(lkb ^ (Ra&3));
  }
  #pragma unroll
  for (int u=0;u<4;u++){
    const int Rb = wc + u*16 + l15;
    boff[u] = Rb*32 + 8*(lkb ^ (Rb&3));
  }

  auto ldB = [&](int st, int py, int px)->ushort8 {
    const int k = k0 + st*32;
    const int t = k>>9;
    const int dy = t/3, dx = t - dy*3;
    const int yy = py + dy - 1, xx = px + dx - 1;
    ushort8 r = {};
    if ((unsigned)yy < 16u && (unsigned)xx < 32u)
      r = *(const ushort8*)(XT + (size_t)(yy*32+xx)*512 + (k&511) + skb*8);
    return r;
  };

  constexpr int NST = KCH/32;
  f32x4 acc[2][4] = {};
  ushort8 ra  = *(const ushort8*)gA;
  ushort8 rb0 = ldB(0, py0, px0);
  ushort8 rb1 = ldB(0, py1, px1);
  *(ushort8*)(&lA[0][soffA])  = ra;
  *(ushort8*)(&lB[0][soffB0]) = rb0;
  *(ushort8*)(&lB[0][soffB1]) = rb1;
  if (NST > 1){
    ra  = *(const ushort8*)(gA+32);
    rb0 = ldB(1, py0, px0);
    rb1 = ldB(1, py1, px1);
  }
  __syncthreads();
  for (int st=0; st<NST; ++st){
    const int cur = st&1;
    bf16x8 af[2], bfr[4];
    #pragma unroll
    for (int s=0;s<2;s++) af[s] = *(const bf16x8*)(&lA[cur][aoff[s]]);
    #pragma unroll
    for (int u=0;u<4;u++) bfr[u] = *(const bf16x8*)(&lB[cur][boff[u]]);
    if (st+1 < NST){
      const int nxt = cur^1;
      *(ushort8*)(&lA[nxt][soffA])  = ra;
      *(ushort8*)(&lB[nxt][soffB0]) = rb0;
      *(ushort8*)(&lB[nxt][soffB1]) = rb1;
      if (st+2 < NST){
        ra  = *(const ushort8*)(gA + (size_t)(st+2)*32);
        rb0 = ldB(st+2, py0, px0);
        rb1 = ldB(st+2, py1, px1);
      }
    }
    #pragma unroll
    for (int s=0;s<2;s++)
      #pragma unroll
      for (int u=0;u<4;u++)
        acc[s][u] = __builtin_amdgcn_mfma_f32_16x16x32_bf16(af[s], bfr[u], acc[s][u], 0,0,0);
    __syncthreads();
  }

  float* pbase = part + (size_t)blockIdx.z*262144;
  #pragma unroll
  for (int s=0;s<2;s++)
    #pragma unroll
    for (int u=0;u<4;u++){
      const int row = m0 + wr + s*16 + lkb*4;
      const int col = n0 + wc + u*16 + l15;
      #pragma unroll
      for (int r=0;r<4;r++)
        pbase[(size_t)(row+r)*512 + col] = acc[s][u][r];
    }
}

// ===== final reduce: bias + partials + residual (float4) =====================
__global__ __launch_bounds__(256) void k_reduce_final(const float* __restrict__ part,
    const float* __restrict__ bias, const float* __restrict__ res,
    float* __restrict__ y, int nchunks){
  const int i = blockIdx.x*256 + threadIdx.x;   // float4 index, 0..65535
  const int o = i>>7;
  const float b = bias[o];
  float4 a4 = {b,b,b,b};
  for (int s=0;s<nchunks;s++){
    const float4 v = ((const float4*)part)[(size_t)s*65536 + i];
    a4.x += v.x; a4.y += v.y; a4.z += v.z; a4.w += v.w;
  }
  const float4 rv = ((const float4*)res)[i];
  a4.x += rv.x; a4.y += rv.y; a4.z += rv.z; a4.w += rv.w;
  ((float4*)y)[i] = a4;
}

extern "C" void kernel_launch(void* const* d_in, const int* in_sizes, int n_in,
                              void* d_out, int out_size, void* d_ws, size_t ws_size,
                              hipStream_t stream) {
  (void)in_sizes; (void)n_in; (void)out_size;
  const float* xin    = (const float*)d_in[0];
  const float* deg    = (const float*)d_in[1];
  const float* k1_w1  = (const float*)d_in[2];
  const float* k1_w2  = (const float*)d_in[3];
  const float* p1_w   = (const float*)d_in[4];
  const float* p1_b   = (const float*)d_in[5];
  const float* ca1_w1 = (const float*)d_in[6];
  const float* ca1_w2 = (const float*)d_in[7];
  const float* conv1_w= (const float*)d_in[8];
  const float* conv1_b= (const float*)d_in[9];
  const float* k2_w1  = (const float*)d_in[10];
  const float* k2_w2  = (const float*)d_in[11];
  const float* p2_w   = (const float*)d_in[12];
  const float* p2_b   = (const float*)d_in[13];
  const float* ca2_w1 = (const float*)d_in[14];
  const float* ca2_w2 = (const float*)d_in[15];
  const float* conv2_w= (const float*)d_in[16];
  const float* conv2_b= (const float*)d_in[17];
  float* out = (float*)d_out;

  // split-K for conv: 16 if workspace allows (adds 8 MB), else 8
  const bool big = ws_size >= (size_t)8202000*4;
  const int NS = big ? 16 : 8;

  // ---- workspace (float units) ----
  float* ws = (float*)d_ws;
  float* PART = ws;  ws += (size_t)NS*262144;
  // aliases into PART: consumed before first k_mfma_conv write
  float* TMP1 = PART;
  float* TMP2 = PART + 262144;
  unsigned short* HID1 = (unsigned short*)(PART + 524288);   // 32768 us
  unsigned short* HID2 = HID1 + 32768;
  float* KERN1 = ws;  ws += 4608;
  float* KERN2 = ws;  ws += 4608;
  float* ATT1  = ws;  ws += 262144;
  float* ATT2  = ws;  ws += 262144;
  unsigned short* DEGB = (unsigned short*)ws; ws += 131072;
  unsigned short* DEGT = (unsigned short*)ws; ws += 131072;
  unsigned short* K1B  = (unsigned short*)ws; ws += 131072;
  unsigned short* K2B  = (unsigned short*)ws; ws += 131072;
  unsigned short* P1B  = (unsigned short*)ws; ws += 131072;
  unsigned short* P2B  = (unsigned short*)ws; ws += 131072;
  unsigned short* CA1A = (unsigned short*)ws; ws += 16384;
  unsigned short* CA1B = (unsigned short*)ws; ws += 16384;
  unsigned short* CA2A = (unsigned short*)ws; ws += 16384;
  unsigned short* CA2B = (unsigned short*)ws; ws += 16384;
  unsigned short* DWLT = (unsigned short*)ws; ws += 131072;
  unsigned short* XT   = (unsigned short*)ws; ws += 131072;
  unsigned short* WB1  = (unsigned short*)ws; ws += 1179648;
  unsigned short* WB2  = (unsigned short*)ws; ws += 1179648;

  // 1. all weight packs
  k_pack_all<<<6272,256,0,stream>>>(k1_w1,k2_w1,p1_w,p2_w,
      ca1_w1,ca1_w2,ca2_w1,ca2_w2, deg, conv1_w, conv2_w,
      K1B,K2B,P1B,P2B, CA1A,CA1B,CA2A,CA2B, DEGB,DEGT, WB1,WB2);

  // 2. TMP{1,2} + HID{1,2}   [z-batched]
  k_mgemm_pre<<<dim3(8,8,4),256,0,stream>>>(DEGB,DEGT, K1B,K2B, CA1A,CA2A,
      TMP1,TMP2, HID1,HID2);
  // 3. KERN{1,2} + ATT{1,2}  [z-batched]
  k_kern_att<<<dim3(128,1,4),256,0,stream>>>(TMP1,TMP2, k1_w2,k2_w2,
      CA1B,CA2B, HID1,HID2, KERN1,KERN2, ATT1,ATT2);

  // 4. da_conv1 depthwise -> DWLT [px][ch] bf16
  k_dwconv<<<512,512,0,stream>>>(xin, KERN1, DWLT);
  // 5. pointwise 1 (+bias+deg*att+lrelu) -> XT
  k_pw<<<dim3(16,16),256,0,stream>>>(P1B, DWLT, p1_b, deg, ATT1, XT);
  // 6. conv1 3x3 (64x128 tile implicit GEMM)
  if (big) k_mfma_conv<288><<<dim3(8,4,16),256,0,stream>>>(WB1, XT, PART);
  else     k_mfma_conv<576><<<dim3(8,4,8), 256,0,stream>>>(WB1, XT, PART);
  // 7. fused reduce+lrelu+depthwise (da_conv2) -> DWLT
  k_dwconv_red<<<512,512,0,stream>>>(PART, conv1_b, KERN2, DWLT, NS);
  // 8. pointwise 2 -> XT
  k_pw<<<dim3(16,16),256,0,stream>>>(P2B, DWLT, p2_b, deg, ATT2, XT);
  // 9. conv2 3x3
  if (big) k_mfma_conv<288><<<dim3(8,4,16),256,0,stream>>>(WB2, XT, PART);
  else     k_mfma_conv<576><<<dim3(8,4,8), 256,0,stream>>>(WB2, XT, PART);
  // 10. final reduce + bias + residual
  k_reduce_final<<<256,256,0,stream>>>(PART, conv2_b, xin, out, NS);
}

// Round 8
// 85.125 us; speedup vs baseline: 5.9019x; 1.0328x over previous
//
#include <hip/hip_runtime.h>
#include <hip/hip_bf16.h>

typedef __attribute__((ext_vector_type(8))) unsigned short ushort8;
typedef __attribute__((ext_vector_type(8))) __bf16 bf16x8;
typedef __attribute__((ext_vector_type(4))) float f32x4;
typedef __attribute__((ext_vector_type(4))) unsigned short ushort4v;

__device__ __forceinline__ float lrelu_f(float v){ return v > 0.f ? v : 0.1f*v; }

__device__ __forceinline__ unsigned short f2bf(float v){
  unsigned u = __float_as_uint(v);
  unsigned r = (u + 0x7fffu + ((u>>16)&1u)) >> 16;
  return (unsigned short)r;
}
__device__ __forceinline__ float bf2f(unsigned short u){
  return __uint_as_float(((unsigned)u)<<16);
}

__device__ __forceinline__ void packq(const float* __restrict__ s,
                                      unsigned short* __restrict__ d, int i){
  const float4 v = ((const float4*)s)[i];
  ushort4v o; o.x=f2bf(v.x); o.y=f2bf(v.y); o.z=f2bf(v.z); o.w=f2bf(v.w);
  *(ushort4v*)(d + (size_t)i*4) = o;
}

// ============ one fused pack kernel: all weights -> bf16 ============
__global__ __launch_bounds__(256) void k_pack_all(
  const float* __restrict__ k1_w1, const float* __restrict__ k2_w1,
  const float* __restrict__ p1_w,  const float* __restrict__ p2_w,
  const float* __restrict__ ca1_w1,const float* __restrict__ ca1_w2,
  const float* __restrict__ ca2_w1,const float* __restrict__ ca2_w2,
  const float* __restrict__ deg,   const float* __restrict__ conv1_w,
  const float* __restrict__ conv2_w,
  unsigned short* __restrict__ K1B, unsigned short* __restrict__ K2B,
  unsigned short* __restrict__ P1B, unsigned short* __restrict__ P2B,
  unsigned short* __restrict__ CA1A,unsigned short* __restrict__ CA1B,
  unsigned short* __restrict__ CA2A,unsigned short* __restrict__ CA2B,
  unsigned short* __restrict__ DEGB,unsigned short* __restrict__ DEGT,
  unsigned short* __restrict__ WB1, unsigned short* __restrict__ WB2){
  int i = blockIdx.x*256 + threadIdx.x;
  if (i < 65536){ packq(k1_w1, K1B, i); return; } i -= 65536;
  if (i < 65536){ packq(k2_w1, K2B, i); return; } i -= 65536;
  if (i < 65536){ packq(p1_w,  P1B, i); return; } i -= 65536;
  if (i < 65536){ packq(p2_w,  P2B, i); return; } i -= 65536;
  if (i < 8192){ packq(ca1_w1, CA1A, i); return; } i -= 8192;
  if (i < 8192){ packq(ca1_w2, CA1B, i); return; } i -= 8192;
  if (i < 8192){ packq(ca2_w1, CA2A, i); return; } i -= 8192;
  if (i < 8192){ packq(ca2_w2, CA2B, i); return; } i -= 8192;
  if (i < 65536){ packq(deg, DEGB, i); return; } i -= 65536;
  if (i < 65536){                      // DEGT: bf16 transpose of deg
    const int j = i*4; const int p = j>>9, c = j&511;
    ushort4v o;
    o.x = f2bf(deg[(size_t)(c+0)*512 + p]);
    o.y = f2bf(deg[(size_t)(c+1)*512 + p]);
    o.z = f2bf(deg[(size_t)(c+2)*512 + p]);
    o.w = f2bf(deg[(size_t)(c+3)*512 + p]);
    *(ushort4v*)(DEGT + (size_t)j) = o;
    return;
  } i -= 65536;
  if (i < 589824){                     // WB1: [o][t*512+ci] = w[o][ci*9+t]
    const int o_ = i/1152; const int r4 = (i - o_*1152)*4;
    const int t = r4>>9; const int ci = r4&511;
    const float* s = conv1_w + (size_t)o_*4608;
    ushort4v o;
    o.x = f2bf(s[(ci+0)*9 + t]); o.y = f2bf(s[(ci+1)*9 + t]);
    o.z = f2bf(s[(ci+2)*9 + t]); o.w = f2bf(s[(ci+3)*9 + t]);
    *(ushort4v*)(WB1 + (size_t)o_*4608 + r4) = o;
    return;
  } i -= 589824;
  if (i < 589824){                     // WB2
    const int o_ = i/1152; const int r4 = (i - o_*1152)*4;
    const int t = r4>>9; const int ci = r4&511;
    const float* s = conv2_w + (size_t)o_*4608;
    ushort4v o;
    o.x = f2bf(s[(ci+0)*9 + t]); o.y = f2bf(s[(ci+1)*9 + t]);
    o.z = f2bf(s[(ci+2)*9 + t]); o.w = f2bf(s[(ci+3)*9 + t]);
    *(ushort4v*)(WB2 + (size_t)o_*4608 + r4) = o;
  }
}

// ======= shared 64x64 MFMA GEMM core, 4 waves, dbuf single-barrier =======
__device__ __forceinline__ void gemm64(
    const unsigned short* __restrict__ A, const unsigned short* __restrict__ Bt,
    int m0, int n0, int K, int tid,
    unsigned short* lA, unsigned short* lB, f32x4 acc[2][2]){
  const int wid = tid>>6, lane = tid&63;
  const int srow = tid>>2, skb = tid&3;
  const unsigned short* gA = A  + (size_t)(m0+srow)*K + skb*8;
  const unsigned short* gB = Bt + (size_t)(n0+srow)*K + skb*8;
  const int soff = srow*32 + 8*(skb ^ (srow&3));
  const int wr = (wid>>1)*32, wc = (wid&1)*32;
  const int l15 = lane&15, lkb = lane>>4;
  int aoff[2], boff[2];
  #pragma unroll
  for (int s=0;s<2;s++){
    const int Ra = wr + s*16 + l15;
    aoff[s] = Ra*32 + 8*(lkb ^ (Ra&3));
    const int Rb = wc + s*16 + l15;
    boff[s] = Rb*32 + 8*(lkb ^ (Rb&3));
  }
  const int nst = K>>5;
  ushort8 ra = *(const ushort8*)gA;
  ushort8 rb = *(const ushort8*)gB;
  *(ushort8*)(lA + soff) = ra;
  *(ushort8*)(lB + soff) = rb;
  if (nst > 1){ ra = *(const ushort8*)(gA+32); rb = *(const ushort8*)(gB+32); }
  __syncthreads();
  for (int st=0; st<nst; ++st){
    const int cur = (st&1)*2048;
    bf16x8 af[2], bfr[2];
    #pragma unroll
    for (int s=0;s<2;s++){
      af[s]  = *(const bf16x8*)(lA + cur + aoff[s]);
      bfr[s] = *(const bf16x8*)(lB + cur + boff[s]);
    }
    if (st+1 < nst){
      const int nxt = ((st+1)&1)*2048;
      *(ushort8*)(lA + nxt + soff) = ra;
      *(ushort8*)(lB + nxt + soff) = rb;
      if (st+2 < nst){
        ra = *(const ushort8*)(gA + (size_t)(st+2)*32);
        rb = *(const ushort8*)(gB + (size_t)(st+2)*32);
      }
    }
    #pragma unroll
    for (int mi=0;mi<2;mi++)
      #pragma unroll
      for (int ni=0;ni<2;ni++)
        acc[mi][ni] = __builtin_amdgcn_mfma_f32_16x16x32_bf16(af[mi], bfr[ni], acc[mi][ni], 0,0,0);
    __syncthreads();
  }
}

// ==== batched pre-GEMMs: z=0,1 TMP{1,2}=lrelu(deg@kw1^T) f32 [512][512] ======
//                         z=2,3 HID{1,2}=lrelu(DEGT@ca_w1^T) bf16 [512][64] ===
__global__ __launch_bounds__(256) void k_mgemm_pre(
    const unsigned short* __restrict__ DEGB, const unsigned short* __restrict__ DEGT,
    const unsigned short* __restrict__ K1B,  const unsigned short* __restrict__ K2B,
    const unsigned short* __restrict__ CA1A, const unsigned short* __restrict__ CA2A,
    float* __restrict__ TMP1, float* __restrict__ TMP2,
    unsigned short* __restrict__ HID1, unsigned short* __restrict__ HID2){
  const int z = blockIdx.z;
  if (z >= 2 && blockIdx.y != 0) return;
  const unsigned short* A  = (z < 2) ? DEGB : DEGT;
  const unsigned short* Bt = (z==0) ? K1B : (z==1) ? K2B : (z==2) ? CA1A : CA2A;
  __shared__ unsigned short lA[4096], lB[4096];
  const int tid = threadIdx.x;
  const int m0 = blockIdx.x*64, n0 = blockIdx.y*64;
  f32x4 acc[2][2] = {};
  gemm64(A, Bt, m0, n0, 512, tid, lA, lB, acc);

  const int wid = tid>>6, lane = tid&63;
  const int wr = (wid>>1)*32, wc = (wid&1)*32;
  const int l15 = lane&15, lkb = lane>>4;
  #pragma unroll
  for (int mi=0;mi<2;mi++)
    #pragma unroll
    for (int ni=0;ni<2;ni++){
      const int row = m0 + wr + mi*16 + lkb*4;
      const int col = n0 + wc + ni*16 + l15;
      #pragma unroll
      for (int r=0;r<4;r++){
        const float v = lrelu_f(acc[mi][ni][r]);
        if (z==0)      TMP1[(size_t)(row+r)*512 + col] = v;
        else if (z==1) TMP2[(size_t)(row+r)*512 + col] = v;
        else if (z==2) HID1[(size_t)(row+r)*64 + col] = f2bf(v);
        else           HID2[(size_t)(row+r)*64 + col] = f2bf(v);
      }
    }
}

// ==== batched: z=0,1 kern_gen ; z=2,3 ATT = sigmoid(ca_w2 @ HID^T) ===========
__global__ __launch_bounds__(256) void k_kern_att(
    const float* __restrict__ TMP1, const float* __restrict__ TMP2,
    const float* __restrict__ kw2a, const float* __restrict__ kw2b,
    const unsigned short* __restrict__ CA1B, const unsigned short* __restrict__ CA2B,
    const unsigned short* __restrict__ HID1, const unsigned short* __restrict__ HID2,
    float* __restrict__ kern0, float* __restrict__ kern1,
    float* __restrict__ ATT1, float* __restrict__ ATT2){
  const int z = blockIdx.z;
  const int tid = threadIdx.x;
  if (z < 2){
    const float* tmp  = z ? TMP2 : TMP1;
    const float* kw2  = z ? kw2b : kw2a;
    float* kern       = z ? kern1 : kern0;
    const int i = blockIdx.x*4 + (tid>>6);
    const int lane = tid&63;
    float acc[9];
    #pragma unroll
    for (int q=0;q<9;q++) acc[q]=0.f;
    for (int j=lane; j<512; j+=64){
      const float t = tmp[i*512 + j];
      #pragma unroll
      for (int q=0;q<9;q++) acc[q] += t*kw2[q*512 + j];
    }
    #pragma unroll
    for (int q=0;q<9;q++){
      float v = acc[q];
      #pragma unroll
      for (int off=32; off>0; off>>=1) v += __shfl_down(v, off);
      if (lane==0) kern[i*9+q] = v;
    }
  } else {
    if (blockIdx.x >= 64) return;
    const unsigned short* A  = (z==2) ? CA1B : CA2B;   // [512][64]
    const unsigned short* Bt = (z==2) ? HID1 : HID2;   // [512][64]
    float* ATT               = (z==2) ? ATT1 : ATT2;
    __shared__ unsigned short lA[4096], lB[4096];
    const int m0 = (blockIdx.x>>3)*64, n0 = (blockIdx.x&7)*64;
    f32x4 acc[2][2] = {};
    gemm64(A, Bt, m0, n0, 64, tid, lA, lB, acc);
    const int wid = tid>>6, lane = tid&63;
    const int wr = (wid>>1)*32, wc = (wid&1)*32;
    const int l15 = lane&15, lkb = lane>>4;
    #pragma unroll
    for (int mi=0;mi<2;mi++)
      #pragma unroll
      for (int ni=0;ni<2;ni++){
        const int row = m0 + wr + mi*16 + lkb*4;
        const int col = n0 + wc + ni*16 + l15;
        #pragma unroll
        for (int r=0;r<4;r++)
          ATT[(size_t)(row+r)*512 + col] = 1.f/(1.f + expf(-acc[mi][ni][r]));
      }
  }
}

// ==== depthwise 3x3 (SAME) + lrelu, f32 input, OUT transposed bf16 [px][ch] ===
__global__ __launch_bounds__(512) void k_dwconv(const float* __restrict__ x,
    const float* __restrict__ kern, unsigned short* __restrict__ yt){
  const int c = blockIdx.x;
  const int p = threadIdx.x;
  const int iy = p>>5, ix = p&31;
  __shared__ float plane[18*34];
  for (int i=p;i<18*34;i+=512) plane[i]=0.f;
  __syncthreads();
  plane[(iy+1)*34 + ix+1] = x[c*512 + p];
  __syncthreads();
  const float* kp = kern + c*9;
  float s = 0.f;
  #pragma unroll
  for (int dy=0;dy<3;dy++)
    #pragma unroll
    for (int dx=0;dx<3;dx++)
      s += plane[(iy+dy)*34 + ix+dx]*kp[dy*3+dx];
  yt[(size_t)p*512 + c] = f2bf(lrelu_f(s));
}

// ==== fused: reduce nchunks bf16 partials + bias + lrelu, then dw -> yt ======
__global__ __launch_bounds__(512) void k_dwconv_red(const unsigned short* __restrict__ part,
    const float* __restrict__ bias, const float* __restrict__ kern,
    unsigned short* __restrict__ yt, int nchunks){
  const int c = blockIdx.x;
  const int p = threadIdx.x;
  const int iy = p>>5, ix = p&31;
  __shared__ float plane[18*34];
  for (int i=p;i<18*34;i+=512) plane[i]=0.f;
  __syncthreads();
  if (p < 128){
    const float b = bias[c];
    float4 a4 = {b,b,b,b};
    for (int s=0;s<nchunks;s++){
      const ushort4v v = ((const ushort4v*)(part + (size_t)s*262144 + c*512))[p];
      a4.x += bf2f(v.x); a4.y += bf2f(v.y); a4.z += bf2f(v.z); a4.w += bf2f(v.w);
    }
    a4.x = lrelu_f(a4.x); a4.y = lrelu_f(a4.y);
    a4.z = lrelu_f(a4.z); a4.w = lrelu_f(a4.w);
    const int px0 = p*4;
    float* dst = &plane[((px0>>5)+1)*34 + (px0&31)+1];
    dst[0]=a4.x; dst[1]=a4.y; dst[2]=a4.z; dst[3]=a4.w;
  }
  __syncthreads();
  const float* kp = kern + c*9;
  float s = 0.f;
  #pragma unroll
  for (int dy=0;dy<3;dy++)
    #pragma unroll
    for (int dx=0;dx<3;dx++)
      s += plane[(iy+dy)*34 + ix+dx]*kp[dy*3+dx];
  yt[(size_t)p*512 + c] = f2bf(lrelu_f(s));
}

// ==== pointwise GEMM 32x32-tile, dbuf single-barrier ====
__global__ __launch_bounds__(256) void k_pw(
    const unsigned short* __restrict__ A, const unsigned short* __restrict__ Bt,
    const float* __restrict__ bias,
    const float* __restrict__ E1, const float* __restrict__ E2,
    unsigned short* __restrict__ XT){
  __shared__ unsigned short lA[2][1024], lB[2][1024];
  __shared__ float tile[32][33];
  const int tid = threadIdx.x;
  const int wid = tid>>6, lane = tid&63;
  const int M0 = blockIdx.x*32, N0 = blockIdx.y*32;

  const int half = tid>>7;                 // 0: stage A, 1: stage B
  const int st_ = tid&127;
  const int srow = st_>>2, skb = st_&3;
  const unsigned short* gS = (half ? Bt + (size_t)(N0+srow)*512
                                   : A  + (size_t)(M0+srow)*512) + skb*8;
  unsigned short (*lS)[1024] = half ? lB : lA;
  const int soff = srow*32 + 8*(skb ^ (srow&3));

  const int wr = (wid>>1)*16, wc = (wid&1)*16;
  const int l15 = lane&15, lkb = lane>>4;
  const int Ra = wr + l15, Rb = wc + l15;
  const int aoff = Ra*32 + 8*(lkb ^ (Ra&3));
  const int boff = Rb*32 + 8*(lkb ^ (Rb&3));

  f32x4 acc = {};
  ushort8 r0 = *(const ushort8*)gS;
  *(ushort8*)(&lS[0][soff]) = r0;
  r0 = *(const ushort8*)(gS+32);
  __syncthreads();
  for (int st=0; st<16; ++st){
    const int cur = st&1;
    const bf16x8 af = *(const bf16x8*)(&lA[cur][aoff]);
    const bf16x8 bf = *(const bf16x8*)(&lB[cur][boff]);
    if (st+1 < 16){
      *(ushort8*)(&lS[cur^1][soff]) = r0;
      if (st+2 < 16) r0 = *(const ushort8*)(gS + (size_t)(st+2)*32);
    }
    acc = __builtin_amdgcn_mfma_f32_16x16x32_bf16(af, bf, acc, 0,0,0);
    __syncthreads();
  }

  #pragma unroll
  for (int r=0;r<4;r++){
    const int rl = wr + lkb*4 + r;
    const int cl = wc + l15;
    const int rr = M0 + rl, col = N0 + cl;
    float v = acc[r] + bias[rr] + E1[(size_t)rr*512+col]*E2[(size_t)rr*512+col];
    tile[rl][cl] = lrelu_f(v);
  }
  __syncthreads();
  const int pr = tid>>3, q = tid&7;
  ushort4v o;
  o.x = f2bf(tile[q*4+0][pr]); o.y = f2bf(tile[q*4+1][pr]);
  o.z = f2bf(tile[q*4+2][pr]); o.w = f2bf(tile[q*4+3][pr]);
  *(ushort4v*)(XT + (size_t)(N0+pr)*512 + M0 + q*4) = o;
}

// ===== conv 3x3 MFMA GEMM 64x128 tile, BK=64 steps, bf16 partials ============
// A = WB [512][4608] (k = t*512+ci), B = XT [512 px][512 ch]; grid (8,4,18)
template<int KCH>   // 256
__global__ __launch_bounds__(256) void k_mfma_conv(
    const unsigned short* __restrict__ WB,
    const unsigned short* __restrict__ XT,
    unsigned short* __restrict__ part){
  __shared__ unsigned short lA[2][4096];   // 64 rows x 64 k
  __shared__ unsigned short lB[2][8192];   // 128 rows x 64 k
  const int tid = threadIdx.x;
  const int wid = tid>>6, lane = tid&63;
  const int m0 = blockIdx.x*64, n0 = blockIdx.y*128;
  const int k0 = blockIdx.z*KCH;

  const int srow = tid>>2, skb = tid&3;     // srow 0..63; kb = skb, skb+4
  const unsigned short* gA = WB + (size_t)(m0+srow)*4608 + k0 + skb*8;
  const int brow1 = srow + 64;
  const int p0 = n0 + srow, p1 = n0 + brow1;
  const int py0 = p0>>5, px0 = p0&31, py1 = p1>>5, px1 = p1&31;
  const int s7 = srow&7;
  const int soffA0 = srow*64 + 8*(skb ^ s7);
  const int soffA1 = srow*64 + 8*((skb+4) ^ s7);
  const int soffB00 = soffA0,            soffB01 = soffA1;
  const int soffB10 = brow1*64 + 8*(skb ^ s7);
  const int soffB11 = brow1*64 + 8*((skb+4) ^ s7);

  const int wr = (wid>>1)*32, wc = (wid&1)*64;
  const int l15 = lane&15, lkb = lane>>4;
  int aoff[2][2], boff[4][2];
  #pragma unroll
  for (int s=0;s<2;s++){
    const int Ra = wr + s*16 + l15;
    #pragma unroll
    for (int h=0;h<2;h++) aoff[s][h] = Ra*64 + 8*((lkb+4*h) ^ (Ra&7));
  }
  #pragma unroll
  for (int u=0;u<4;u++){
    const int Rb = wc + u*16 + l15;
    #pragma unroll
    for (int h=0;h<2;h++) boff[u][h] = Rb*64 + 8*((lkb+4*h) ^ (Rb&7));
  }

  auto ldB = [&](int st, int py, int px, ushort8& lo, ushort8& hi){
    const int k = k0 + st*64;               // 64 | 512 => t const per step
    const int t = k>>9;
    const int dy = t/3, dx = t - dy*3;
    const int yy = py + dy - 1, xx = px + dx - 1;
    lo = (ushort8){}; hi = (ushort8){};
    if ((unsigned)yy < 16u && (unsigned)xx < 32u){
      const unsigned short* b = XT + (size_t)(yy*32+xx)*512 + (k&511) + skb*8;
      lo = *(const ushort8*)b; hi = *(const ushort8*)(b+32);
    }
  };

  constexpr int NST = KCH/64;               // 4
  f32x4 acc[2][4] = {};
  ushort8 ra0 = *(const ushort8*)gA;
  ushort8 ra1 = *(const ushort8*)(gA+32);
  ushort8 b00,b01,b10,b11;
  ldB(0, py0, px0, b00, b01);
  ldB(0, py1, px1, b10, b11);
  *(ushort8*)(&lA[0][soffA0]) = ra0;  *(ushort8*)(&lA[0][soffA1]) = ra1;
  *(ushort8*)(&lB[0][soffB00]) = b00; *(ushort8*)(&lB[0][soffB01]) = b01;
  *(ushort8*)(&lB[0][soffB10]) = b10; *(ushort8*)(&lB[0][soffB11]) = b11;
  if (NST > 1){
    ra0 = *(const ushort8*)(gA+64); ra1 = *(const ushort8*)(gA+96);
    ldB(1, py0, px0, b00, b01);
    ldB(1, py1, px1, b10, b11);
  }
  __syncthreads();
  for (int st=0; st<NST; ++st){
    const int cur = st&1;
    bf16x8 af[2][2], bfr[4][2];
    #pragma unroll
    for (int s=0;s<2;s++)
      #pragma unroll
      for (int h=0;h<2;h++) af[s][h] = *(const bf16x8*)(&lA[cur][aoff[s][h]]);
    #pragma unroll
    for (int u=0;u<4;u++)
      #pragma unroll
      for (int h=0;h<2;h++) bfr[u][h] = *(const bf16x8*)(&lB[cur][boff[u][h]]);
    if (st+1 < NST){
      const int nxt = cur^1;
      *(ushort8*)(&lA[nxt][soffA0]) = ra0;  *(ushort8*)(&lA[nxt][soffA1]) = ra1;
      *(ushort8*)(&lB[nxt][soffB00]) = b00; *(ushort8*)(&lB[nxt][soffB01]) = b01;
      *(ushort8*)(&lB[nxt][soffB10]) = b10; *(ushort8*)(&lB[nxt][soffB11]) = b11;
      if (st+2 < NST){
        ra0 = *(const ushort8*)(gA + (size_t)(st+2)*64);
        ra1 = *(const ushort8*)(gA + (size_t)(st+2)*64 + 32);
        ldB(st+2, py0, px0, b00, b01);
        ldB(st+2, py1, px1, b10, b11);
      }
    }
    #pragma unroll
    for (int h=0;h<2;h++)
      #pragma unroll
      for (int s=0;s<2;s++)
        #pragma unroll
        for (int u=0;u<4;u++)
          acc[s][u] = __builtin_amdgcn_mfma_f32_16x16x32_bf16(af[s][h], bfr[u][h], acc[s][u], 0,0,0);
    __syncthreads();
  }

  unsigned short* pbase = part + (size_t)blockIdx.z*262144;
  #pragma unroll
  for (int s=0;s<2;s++)
    #pragma unroll
    for (int u=0;u<4;u++){
      const int row = m0 + wr + s*16 + lkb*4;
      const int col = n0 + wc + u*16 + l15;
      #pragma unroll
      for (int r=0;r<4;r++)
        pbase[(size_t)(row+r)*512 + col] = f2bf(acc[s][u][r]);
    }
}

// ===== final reduce: bias + bf16 partials + residual =========================
__global__ __launch_bounds__(256) void k_reduce_final(const unsigned short* __restrict__ part,
    const float* __restrict__ bias, const float* __restrict__ res,
    float* __restrict__ y, int nchunks){
  const int i = blockIdx.x*256 + threadIdx.x;   // quad index, 0..65535
  const int o = i>>7;
  const float b = bias[o];
  float4 a4 = {b,b,b,b};
  for (int s=0;s<nchunks;s++){
    const ushort4v v = ((const ushort4v*)part)[(size_t)s*65536 + i];
    a4.x += bf2f(v.x); a4.y += bf2f(v.y); a4.z += bf2f(v.z); a4.w += bf2f(v.w);
  }
  const float4 rv = ((const float4*)res)[i];
  a4.x += rv.x; a4.y += rv.y; a4.z += rv.z; a4.w += rv.w;
  ((float4*)y)[i] = a4;
}

extern "C" void kernel_launch(void* const* d_in, const int* in_sizes, int n_in,
                              void* d_out, int out_size, void* d_ws, size_t ws_size,
                              hipStream_t stream) {
  (void)in_sizes; (void)n_in; (void)out_size; (void)ws_size;
  const float* xin    = (const float*)d_in[0];
  const float* deg    = (const float*)d_in[1];
  const float* k1_w1  = (const float*)d_in[2];
  const float* k1_w2  = (const float*)d_in[3];
  const float* p1_w   = (const float*)d_in[4];
  const float* p1_b   = (const float*)d_in[5];
  const float* ca1_w1 = (const float*)d_in[6];
  const float* ca1_w2 = (const float*)d_in[7];
  const float* conv1_w= (const float*)d_in[8];
  const float* conv1_b= (const float*)d_in[9];
  const float* k2_w1  = (const float*)d_in[10];
  const float* k2_w2  = (const float*)d_in[11];
  const float* p2_w   = (const float*)d_in[12];
  const float* p2_b   = (const float*)d_in[13];
  const float* ca2_w1 = (const float*)d_in[14];
  const float* ca2_w2 = (const float*)d_in[15];
  const float* conv2_w= (const float*)d_in[16];
  const float* conv2_b= (const float*)d_in[17];
  float* out = (float*)d_out;

  const int NS = 18;                       // split-K chunks (K=4608, KCH=256)

  // ---- workspace ----
  float* ws = (float*)d_ws;
  unsigned short* PART = (unsigned short*)ws;           // 18*262144 ushorts
  ws += (size_t)NS*131072;                              // = 9.4 MB
  // aliases into PART region: consumed before first conv writes PART
  float* TMP1 = (float*)PART;                           // 1 MB
  float* TMP2 = TMP1 + 262144;                          // 1 MB
  unsigned short* HID1 = (unsigned short*)(TMP2 + 262144);
  unsigned short* HID2 = HID1 + 32768;
  float* KERN1 = ws;  ws += 4608;
  float* KERN2 = ws;  ws += 4608;
  float* ATT1  = ws;  ws += 262144;
  float* ATT2  = ws;  ws += 262144;
  unsigned short* DEGB = (unsigned short*)ws; ws += 131072;
  unsigned short* DEGT = (unsigned short*)ws; ws += 131072;
  unsigned short* K1B  = (unsigned short*)ws; ws += 131072;
  unsigned short* K2B  = (unsigned short*)ws; ws += 131072;
  unsigned short* P1B  = (unsigned short*)ws; ws += 131072;
  unsigned short* P2B  = (unsigned short*)ws; ws += 131072;
  unsigned short* CA1A = (unsigned short*)ws; ws += 16384;
  unsigned short* CA1B = (unsigned short*)ws; ws += 16384;
  unsigned short* CA2A = (unsigned short*)ws; ws += 16384;
  unsigned short* CA2B = (unsigned short*)ws; ws += 16384;
  unsigned short* DWLT = (unsigned short*)ws; ws += 131072;
  unsigned short* XT   = (unsigned short*)ws; ws += 131072;
  unsigned short* WB1  = (unsigned short*)ws; ws += 1179648;
  unsigned short* WB2  = (unsigned short*)ws; ws += 1179648;

  // 1. all weight packs
  k_pack_all<<<6272,256,0,stream>>>(k1_w1,k2_w1,p1_w,p2_w,
      ca1_w1,ca1_w2,ca2_w1,ca2_w2, deg, conv1_w, conv2_w,
      K1B,K2B,P1B,P2B, CA1A,CA1B,CA2A,CA2B, DEGB,DEGT, WB1,WB2);

  // 2. TMP{1,2} + HID{1,2}   [z-batched]
  k_mgemm_pre<<<dim3(8,8,4),256,0,stream>>>(DEGB,DEGT, K1B,K2B, CA1A,CA2A,
      TMP1,TMP2, HID1,HID2);
  // 3. KERN{1,2} + ATT{1,2}  [z-batched]
  k_kern_att<<<dim3(128,1,4),256,0,stream>>>(TMP1,TMP2, k1_w2,k2_w2,
      CA1B,CA2B, HID1,HID2, KERN1,KERN2, ATT1,ATT2);

  // 4. da_conv1 depthwise -> DWLT [px][ch] bf16
  k_dwconv<<<512,512,0,stream>>>(xin, KERN1, DWLT);
  // 5. pointwise 1 (+bias+deg*att+lrelu) -> XT
  k_pw<<<dim3(16,16),256,0,stream>>>(P1B, DWLT, p1_b, deg, ATT1, XT);
  // 6. conv1 3x3 (64x128 tile, BK=64, split-K=18)
  k_mfma_conv<256><<<dim3(8,4,18),256,0,stream>>>(WB1, XT, PART);
  // 7. fused reduce+lrelu+depthwise (da_conv2) -> DWLT
  k_dwconv_red<<<512,512,0,stream>>>(PART, conv1_b, KERN2, DWLT, NS);
  // 8. pointwise 2 -> XT
  k_pw<<<dim3(16,16),256,0,stream>>>(P2B, DWLT, p2_b, deg, ATT2, XT);
  // 9. conv2 3x3
  k_mfma_conv<256><<<dim3(8,4,18),256,0,stream>>>(WB2, XT, PART);
  // 10. final reduce + bias + residual
  k_reduce_final<<<256,256,0,stream>>>(PART, conv2_b, xin, out, NS);
}